// Round 1
// baseline (1691.362 us; speedup 1.0000x reference)
//
#include <hip/hip_runtime.h>
#include <math.h>

// ---------------- constants ----------------
// B=128, W=64, L=4096, MODES=32, N_LAYERS=4, LIFT_L=64
#define GELU_K 0.70710678118654752440f

__device__ __forceinline__ float gelu_f(float x){
    return 0.5f * x * (1.0f + erff(x * GELU_K));
}

// ---------------- workspace layout (float offsets) ----------------
// xbuf   : [128][64][4096]            x / h (in-place per layer)
// modesX : [b][ci][32][2]             DFT output (Xr, Xi)
// modesA : [b][co][64]                scaled iDFT coeffs (32 cos rows, 32 sin rows)
// cond   : [b][64]
// tabC/S : [32][4096]                 cos/sin(2*pi*m*n/4096)
// part   : [b][co][16][2]             per-n-tile (sum, sumsq) partials
// stats  : [b][co][2]                 (mu, rstd)
// dftp   : [ks=8][b][ci][m2=64]       K-split DFT partials
static const size_t OFF_XBUF  = 0;
static const size_t OFF_MX    = 33554432;
static const size_t OFF_MA    = OFF_MX    + 524288;
static const size_t OFF_COND  = OFF_MA    + 524288;
static const size_t OFF_TABC  = OFF_COND  + 8192;
static const size_t OFF_TABS  = OFF_TABC  + 131072;
static const size_t OFF_PART  = OFF_TABS  + 131072;
static const size_t OFF_STATS = OFF_PART  + 262144;
static const size_t OFF_DFTP  = OFF_STATS + 16384;
// total = 39,346,176 floats = ~150 MB

// ---------------- trig tables ----------------
__global__ void k_tab(float* __restrict__ tabC, float* __restrict__ tabS){
    int t = blockIdx.x*256 + threadIdx.x;        // 32*4096 = 131072 threads
    if (t >= 32*4096) return;
    int m = t >> 12, n = t & 4095;
    int r = (m*n) & 4095;
    double a = (double)r * (6.283185307179586476925286766559 / 4096.0);
    tabC[t] = (float)cos(a);
    tabS[t] = (float)sin(a);
}

// ---------------- conditioning MLP: cond[b][64] ----------------
__global__ __launch_bounds__(64) void k_cond(const float* __restrict__ instp,
        const float* __restrict__ w1, const float* __restrict__ b1,
        const float* __restrict__ w2, const float* __restrict__ b2,
        float* __restrict__ cond){
    int b = blockIdx.x, tid = threadIdx.x;
    __shared__ float ipl[8];
    __shared__ float tl[64];
    if (tid < 8) ipl[tid] = instp[b*8 + tid];
    __syncthreads();
    float s = b1[tid];
    #pragma unroll
    for (int k = 0; k < 8; ++k) s = fmaf(ipl[k], w1[k*64 + tid], s);
    tl[tid] = gelu_f(s);
    __syncthreads();
    float c = b2[tid];
    #pragma unroll 8
    for (int j = 0; j < 64; ++j) c = fmaf(tl[j], w2[j*64 + tid], c);
    cond[b*64 + tid] = c;
}

// ---------------- lift + linear interp (64 -> 4096) + cond ----------------
__global__ __launch_bounds__(256) void k_lift(const float* __restrict__ z,
        const float* __restrict__ lw, const float* __restrict__ lb,
        const float* __restrict__ cond, float* __restrict__ xbuf){
    int bid = blockIdx.x;
    int b = bid >> 6, wc = bid & 63;
    int tid = threadIdx.x;
    __shared__ float zl[128];
    __shared__ float x0[64];
    if (tid < 128) zl[tid] = z[b*128 + tid];
    __syncthreads();
    if (tid < 64){
        float s = lb[wc*64 + tid];
        #pragma unroll 4
        for (int d = 0; d < 128; ++d) s = fmaf(zl[d], lw[d*4096 + wc*64 + tid], s);
        x0[tid] = s + cond[b*64 + wc];   // adding cond pre-interp == post-interp (weights sum to 1)
    }
    __syncthreads();
    float* xrow = xbuf + (size_t)(b*64 + wc)*4096;
    #pragma unroll
    for (int r = 0; r < 16; ++r){
        int n = r*256 + tid;
        float src = (n + 0.5f)*0.015625f - 0.5f;          // *(64/4096)
        src = fminf(fmaxf(src, 0.0f), 63.0f);
        int i0 = (int)src;
        int i1 = (i0 + 1 > 63) ? 63 : (i0 + 1);
        float w = src - (float)i0;
        xrow[n] = x0[i0] + w*(x0[i1] - x0[i0]);
    }
}

// ---------------- forward DFT (32 modes), K-split GEMM ----------------
// grid (b=128, ks=8), 64 threads (1 wave). C[m2][ci] = sum_n tab[m2][n]*x[b][ci][n]
__global__ __launch_bounds__(64) void k_dft(const float* __restrict__ xbuf,
        const float* __restrict__ tabC, const float* __restrict__ tabS,
        float* __restrict__ dftp){
    int b = blockIdx.x, ks = blockIdx.y;
    int n0 = ks*512;
    int tid = threadIdx.x;
    int tm = tid >> 3, tn = tid & 7;
    __shared__ float Alds[64*66];   // [k][m2], stride 66 (2-way max bank alias)
    __shared__ float Blds[64*66];   // [k][ci]
    float acc[8][8] = {};
    for (int kc = 0; kc < 512; kc += 64){
        __syncthreads();
        #pragma unroll 4
        for (int i = 0; i < 32; ++i){
            Alds[tid*66 + i]      = tabC[i*4096 + n0 + kc + tid];
            Alds[tid*66 + 32 + i] = tabS[i*4096 + n0 + kc + tid];
        }
        #pragma unroll 4
        for (int i = 0; i < 64; ++i){
            Blds[tid*66 + i] = xbuf[(size_t)(b*64 + i)*4096 + n0 + kc + tid];
        }
        __syncthreads();
        #pragma unroll 2
        for (int k = 0; k < 64; ++k){
            const float* Ap = &Alds[k*66 + tm*8];
            const float* Bp = &Blds[k*66 + tn*8];
            float2 a0 = *(const float2*)(Ap+0);
            float2 a1 = *(const float2*)(Ap+2);
            float2 a2 = *(const float2*)(Ap+4);
            float2 a3 = *(const float2*)(Ap+6);
            float2 c0 = *(const float2*)(Bp+0);
            float2 c1 = *(const float2*)(Bp+2);
            float2 c2 = *(const float2*)(Bp+4);
            float2 c3 = *(const float2*)(Bp+6);
            float av[8] = {a0.x,a0.y,a1.x,a1.y,a2.x,a2.y,a3.x,a3.y};
            float bv[8] = {c0.x,c0.y,c1.x,c1.y,c2.x,c2.y,c3.x,c3.y};
            #pragma unroll
            for (int ii = 0; ii < 8; ++ii)
                #pragma unroll
                for (int jj = 0; jj < 8; ++jj)
                    acc[ii][jj] = fmaf(av[ii], bv[jj], acc[ii][jj]);
        }
    }
    #pragma unroll
    for (int jj = 0; jj < 8; ++jj){
        int ci = tn*8 + jj;
        int base = ((ks*128 + b)*64 + ci)*64 + tm*8;
        #pragma unroll
        for (int ii = 0; ii < 8; ++ii) dftp[base + ii] = acc[ii][jj];
    }
}

// reduce K-slices -> modesX (Xr = sum cos, Xi = -sum sin)
__global__ void k_dftred(const float* __restrict__ dftp, float* __restrict__ mx){
    int t = blockIdx.x*256 + threadIdx.x;     // 262144 = b*2048 + ci*32 + m
    int m  = t & 31;
    int ci = (t >> 5) & 63;
    int b  = t >> 11;
    float cs = 0.f, ss = 0.f;
    #pragma unroll
    for (int ks = 0; ks < 8; ++ks){
        int base = ((ks*128 + b)*64 + ci)*64;
        cs += dftp[base + m];
        ss += dftp[base + 32 + m];
    }
    mx[t*2]   = cs;
    mx[t*2+1] = -ss;
}

// ---------------- spectral channel mix + iDFT coefficient prep ----------------
// grid (b=128, m=32), 64 threads (co). spec_w index (((l*64+ci)*64+co)*32+m)*2 + ri
__global__ __launch_bounds__(64) void k_mix(const float* __restrict__ mx,
        const float* __restrict__ specw, float* __restrict__ ma, int l){
    int b = blockIdx.x, m = blockIdx.y;
    int tid = threadIdx.x;
    __shared__ float xr[64], xi[64];
    int mi = ((b*64 + tid)*32 + m)*2;
    xr[tid] = mx[mi]; xi[tid] = mx[mi+1];
    __syncthreads();
    float yr = 0.f, yi = 0.f;
    const float* wb = specw + (size_t)l*262144 + tid*64 + 2*m;   // (l, ci=0, co=tid, m); ci stride 4096
    #pragma unroll 4
    for (int ci = 0; ci < 64; ++ci){
        float wr  = wb[ci*4096];
        float wiv = wb[ci*4096 + 1];
        yr += xr[ci]*wr  - xi[ci]*wiv;
        yi += xr[ci]*wiv + xi[ci]*wr;
    }
    float sc = (m == 0 ? 1.f : 2.f) * (1.f/4096.f);
    ma[(b*64 + tid)*64 + m]      = sc*yr;            // cos-row coeff
    ma[(b*64 + tid)*64 + 32 + m] = -(2.f/4096.f)*yi; // sin-row coeff (row 0 multiplies sin(0)=0)
}

// ---------------- fused pointwise conv + iDFT -> h (in place) + stats partials ----------------
// grid (b=128, tile=16), 256 threads. H(64x256) = A(64x128) @ B(128x256)
// A rows: [W_pw | cos-coeff | sin-coeff]; B rows: [x(64); tabC(32); tabS(32)]
__global__ __launch_bounds__(256) void k_pass3(float* xbuf,
        const float* __restrict__ pww, const float* __restrict__ pwb,
        const float* __restrict__ ma,  const float* __restrict__ tabC,
        const float* __restrict__ tabS, float* __restrict__ part, int l){
    int b = blockIdx.x, tile = blockIdx.y;
    int n0 = tile*256;
    int tid = threadIdx.x;
    int tm = tid >> 5, tn = tid & 31;
    __shared__ float Alds[128*66];   // [kk][co]
    __shared__ float Blds[16*256];   // [k-local][n]
    #pragma unroll 4
    for (int i = 0; i < 32; ++i){    // stage A (once)
        int e = i*256 + tid;
        int co = e >> 7, kk = e & 127;
        float v = (kk < 64) ? pww[(l*64 + co)*64 + kk]
                            : ma[(b*64 + co)*64 + (kk - 64)];
        Alds[kk*66 + co] = v;
    }
    float acc[8][8] = {};
    for (int c = 0; c < 8; ++c){
        __syncthreads();
        #pragma unroll
        for (int i = 0; i < 16; ++i){
            int kk = c*16 + i;
            const float* src = (kk < 64) ? (xbuf + (size_t)(b*64 + kk)*4096)
                             : (kk < 96) ? (tabC + (kk - 64)*4096)
                                         : (tabS + (kk - 96)*4096);
            Blds[i*256 + tid] = src[n0 + tid];
        }
        __syncthreads();
        #pragma unroll 4
        for (int k = 0; k < 16; ++k){
            int kkg = c*16 + k;
            const float* Ap = &Alds[kkg*66 + tm*8];
            float2 a0 = *(const float2*)(Ap+0);
            float2 a1 = *(const float2*)(Ap+2);
            float2 a2 = *(const float2*)(Ap+4);
            float2 a3 = *(const float2*)(Ap+6);
            float av[8] = {a0.x,a0.y,a1.x,a1.y,a2.x,a2.y,a3.x,a3.y};
            float2 bp[4];
            bp[0] = *(const float2*)&Blds[k*256 + 2*tn];
            bp[1] = *(const float2*)&Blds[k*256 + 2*tn + 64];
            bp[2] = *(const float2*)&Blds[k*256 + 2*tn + 128];
            bp[3] = *(const float2*)&Blds[k*256 + 2*tn + 192];
            #pragma unroll
            for (int ii = 0; ii < 8; ++ii){
                float a = av[ii];
                #pragma unroll
                for (int jp = 0; jp < 4; ++jp){
                    acc[ii][2*jp]   = fmaf(a, bp[jp].x, acc[ii][2*jp]);
                    acc[ii][2*jp+1] = fmaf(a, bp[jp].y, acc[ii][2*jp+1]);
                }
            }
        }
    }
    // epilogue: h = acc + pw_b; write in place; per-row partial sums
    float sS[8], sQ[8];
    #pragma unroll
    for (int i = 0; i < 8; ++i){
        int co = tm*8 + i;
        float pb = pwb[l*64 + co];
        float* xrow = xbuf + (size_t)(b*64 + co)*4096 + n0;
        float s = 0.f, q = 0.f;
        #pragma unroll
        for (int jp = 0; jp < 4; ++jp){
            float h0 = acc[i][2*jp]   + pb;
            float h1 = acc[i][2*jp+1] + pb;
            *(float2*)(xrow + 2*tn + 64*jp) = make_float2(h0, h1);
            s += h0 + h1;
            q = fmaf(h0, h0, q); q = fmaf(h1, h1, q);
        }
        sS[i] = s; sQ[i] = q;
    }
    __syncthreads();
    #pragma unroll
    for (int i = 0; i < 8; ++i){
        Blds[(tm*8 + i)*32 + tn]        = sS[i];
        Blds[2048 + (tm*8 + i)*32 + tn] = sQ[i];
    }
    __syncthreads();
    if (tid < 64){
        float S = 0.f, Q = 0.f;
        #pragma unroll 8
        for (int t = 0; t < 32; ++t){ S += Blds[tid*32 + t]; Q += Blds[2048 + tid*32 + t]; }
        int pi = ((b*64 + tid)*16 + tile)*2;
        part[pi] = S; part[pi+1] = Q;
    }
}

// ---------------- stats reduce ----------------
__global__ void k_stats(const float* __restrict__ part, float* __restrict__ stats){
    int t = blockIdx.x*256 + threadIdx.x;    // 8192 = b*64+co
    if (t >= 8192) return;
    float S = 0.f, Q = 0.f;
    #pragma unroll
    for (int i = 0; i < 16; ++i){ S += part[(t*16+i)*2]; Q += part[(t*16+i)*2+1]; }
    float mu  = S * (1.f/4096.f);
    float var = Q * (1.f/4096.f) - mu*mu;
    stats[t*2]   = mu;
    stats[t*2+1] = rsqrtf(var + 1e-5f);
}

// ---------------- instance-norm + GELU (in place, float4) ----------------
__global__ void k_norm(float* xbuf, const float* __restrict__ stats){
    int i = blockIdx.x*blockDim.x + threadIdx.x;
    int stride = gridDim.x*blockDim.x;
    float4* x4 = (float4*)xbuf;
    for (int f = i; f < 8388608; f += stride){
        int row = f >> 10;
        float mu = stats[row*2], rs = stats[row*2+1];
        float4 v = x4[f];
        v.x = gelu_f((v.x - mu)*rs);
        v.y = gelu_f((v.y - mu)*rs);
        v.z = gelu_f((v.z - mu)*rs);
        v.w = gelu_f((v.w - mu)*rs);
        x4[f] = v;
    }
}

// ---------------- fused projection head ----------------
// grid (b=128, tile=32 of 128 cols), 256 threads. H1 = gelu(W1(128x64)@X + b1); out = w2@H1 + b2
__global__ __launch_bounds__(256) void k_proj(const float* __restrict__ xbuf,
        const float* __restrict__ w1, const float* __restrict__ b1,
        const float* __restrict__ w2, const float* __restrict__ b2,
        float* __restrict__ out){
    int b = blockIdx.x, tile = blockIdx.y;
    int n0 = tile*128;
    int tid = threadIdx.x;
    int tm = tid >> 4, tn = tid & 15;
    __shared__ float Alds[64*130];   // [k][o2]
    __shared__ float Blds[32*128];   // [k-local][n]
    #pragma unroll 4
    for (int i = 0; i < 32; ++i){
        int e = i*256 + tid;
        int o2 = e >> 6, k = e & 63;
        Alds[k*130 + o2] = w1[o2*64 + k];
    }
    float acc[8][8] = {};
    for (int c = 0; c < 2; ++c){
        __syncthreads();
        #pragma unroll
        for (int i = 0; i < 16; ++i){
            int e = i*256 + tid;
            int kr = e >> 7, col = e & 127;
            Blds[kr*128 + col] = xbuf[(size_t)(b*64 + c*32 + kr)*4096 + n0 + col];
        }
        __syncthreads();
        #pragma unroll 4
        for (int kk = 0; kk < 32; ++kk){
            int kg = c*32 + kk;
            const float* Ap = &Alds[kg*130 + tm*8];
            float2 a0 = *(const float2*)(Ap+0);
            float2 a1 = *(const float2*)(Ap+2);
            float2 a2 = *(const float2*)(Ap+4);
            float2 a3 = *(const float2*)(Ap+6);
            float av[8] = {a0.x,a0.y,a1.x,a1.y,a2.x,a2.y,a3.x,a3.y};
            float2 bp[4];
            bp[0] = *(const float2*)&Blds[kk*128 + 2*tn];
            bp[1] = *(const float2*)&Blds[kk*128 + 2*tn + 32];
            bp[2] = *(const float2*)&Blds[kk*128 + 2*tn + 64];
            bp[3] = *(const float2*)&Blds[kk*128 + 2*tn + 96];
            #pragma unroll
            for (int ii = 0; ii < 8; ++ii){
                float a = av[ii];
                #pragma unroll
                for (int jp = 0; jp < 4; ++jp){
                    acc[ii][2*jp]   = fmaf(a, bp[jp].x, acc[ii][2*jp]);
                    acc[ii][2*jp+1] = fmaf(a, bp[jp].y, acc[ii][2*jp+1]);
                }
            }
        }
    }
    float pout[8] = {0.f,0.f,0.f,0.f,0.f,0.f,0.f,0.f};
    #pragma unroll
    for (int i = 0; i < 8; ++i){
        int o2 = tm*8 + i;
        float bb = b1[o2], wv = w2[o2];
        #pragma unroll
        for (int jj = 0; jj < 8; ++jj)
            pout[jj] = fmaf(wv, gelu_f(acc[i][jj] + bb), pout[jj]);
    }
    __syncthreads();
    #pragma unroll
    for (int jp = 0; jp < 4; ++jp){
        Blds[tm*128 + 2*tn + 32*jp]     = pout[2*jp];
        Blds[tm*128 + 2*tn + 32*jp + 1] = pout[2*jp+1];
    }
    __syncthreads();
    if (tid < 128){
        float S = b2[0];
        #pragma unroll
        for (int t = 0; t < 16; ++t) S += Blds[t*128 + tid];
        out[(size_t)b*4096 + n0 + tid] = S;
    }
}

// ---------------- launch ----------------
extern "C" void kernel_launch(void* const* d_in, const int* in_sizes, int n_in,
                              void* d_out, int out_size, void* d_ws, size_t ws_size,
                              hipStream_t stream) {
    (void)in_sizes; (void)n_in; (void)out_size; (void)ws_size;
    const float* z      = (const float*)d_in[0];
    const float* instp  = (const float*)d_in[1];
    const float* lift_w = (const float*)d_in[2];
    const float* lift_b = (const float*)d_in[3];
    const float* iw1    = (const float*)d_in[4];
    const float* ib1    = (const float*)d_in[5];
    const float* iw2    = (const float*)d_in[6];
    const float* ib2    = (const float*)d_in[7];
    const float* specw  = (const float*)d_in[8];
    const float* pww    = (const float*)d_in[9];
    const float* pwb    = (const float*)d_in[10];
    const float* pj1w   = (const float*)d_in[11];
    const float* pj1b   = (const float*)d_in[12];
    const float* pj2w   = (const float*)d_in[13];
    const float* pj2b   = (const float*)d_in[14];

    float* ws    = (float*)d_ws;
    float* xbuf  = ws + OFF_XBUF;
    float* mx    = ws + OFF_MX;
    float* ma    = ws + OFF_MA;
    float* cond  = ws + OFF_COND;
    float* tabC  = ws + OFF_TABC;
    float* tabS  = ws + OFF_TABS;
    float* part  = ws + OFF_PART;
    float* stats = ws + OFF_STATS;
    float* dftp  = ws + OFF_DFTP;
    float* out   = (float*)d_out;

    k_tab <<<dim3(512),  dim3(256), 0, stream>>>(tabC, tabS);
    k_cond<<<dim3(128),  dim3(64),  0, stream>>>(instp, iw1, ib1, iw2, ib2, cond);
    k_lift<<<dim3(8192), dim3(256), 0, stream>>>(z, lift_w, lift_b, cond, xbuf);

    for (int l = 0; l < 4; ++l){
        k_dft   <<<dim3(128, 8),  dim3(64),  0, stream>>>(xbuf, tabC, tabS, dftp);
        k_dftred<<<dim3(1024),    dim3(256), 0, stream>>>(dftp, mx);
        k_mix   <<<dim3(128, 32), dim3(64),  0, stream>>>(mx, specw, ma, l);
        k_pass3 <<<dim3(128, 16), dim3(256), 0, stream>>>(xbuf, pww, pwb, ma, tabC, tabS, part, l);
        k_stats <<<dim3(32),      dim3(256), 0, stream>>>(part, stats);
        k_norm  <<<dim3(4096),    dim3(256), 0, stream>>>(xbuf, stats);
    }
    k_proj<<<dim3(128, 32), dim3(256), 0, stream>>>(xbuf, pj1w, pj1b, pj2w, pj2b, out);
}

// Round 3
// 970.885 us; speedup vs baseline: 1.7421x; 1.7421x over previous
//
#include <hip/hip_runtime.h>
#include <math.h>

// B=128, W=64, L=4096, MODES=32, N_LAYERS=4
#define GELU_K 0.70710678118654752440f

typedef _Float16 half8 __attribute__((ext_vector_type(8)));  // 8 fp16 (4 VGPR)
typedef __attribute__((ext_vector_type(4))) float fx4;       // MFMA f32 acc

__device__ __forceinline__ float gelu_f(float x){
    return 0.5f * x * (1.0f + erff(x * GELU_K));
}
__device__ __forceinline__ unsigned short f2h(float f){      // RNE f32->fp16
    union { _Float16 h; unsigned short u; } c;
    c.h = (_Float16)f;
    return c.u;
}
__device__ __forceinline__ float h2f(unsigned short u){
    union { unsigned short u; _Float16 h; } c;
    c.u = u;
    return (float)c.h;
}
__device__ __forceinline__ half8 cvt8(float4 a, float4 b){
    union { _Float16 h[8]; half8 v; } r;
    r.h[0]=(_Float16)a.x; r.h[1]=(_Float16)a.y; r.h[2]=(_Float16)a.z; r.h[3]=(_Float16)a.w;
    r.h[4]=(_Float16)b.x; r.h[5]=(_Float16)b.y; r.h[6]=(_Float16)b.z; r.h[7]=(_Float16)b.w;
    return r.v;
}

// ---------------- workspace layout (float-slot offsets) ----------------
// xh   : fp16 [128][64][4096]   h / x0 (channel-major)
// xT   : fp16 [128][4096][64]   normalized x, position-major (MFMA k=ci)
// tabB : fp16 [64][4096]        rows 0-31 cos(2pi m n/L), 32-63 sin  (unscaled, fwd DFT)
// tabT : fp16 [4096][64]        transpose, SCALED by 1/64 (iDFT only)
// mx   : f32  [b][ci][32][2]    DFT modes (Xr, Xi)
// ma   : f32  [b][co][64]       iDFT coeffs x64 (32 cos | 32 sin)
// cond : f32  [b][64]
// part : f32  [b][co][16][2]
// stats: f32  [b][co][2]
// dftp : f32  [b][ng=8][64 m2][64 ci]
static const size_t OFF_XH    = 0;                       // 16,777,216
static const size_t OFF_XT    = 16777216;                // 16,777,216
static const size_t OFF_TABB  = 33554432;                // 131,072
static const size_t OFF_TABT  = 33685504;                // 131,072
static const size_t OFF_MX    = 33816576;                // 524,288
static const size_t OFF_MA    = 34340864;                // 524,288
static const size_t OFF_COND  = 34865152;                // 8,192
static const size_t OFF_PART  = 34873344;                // 262,144
static const size_t OFF_STATS = 35135488;                // 16,384
static const size_t OFF_DFTP  = 35151872;                // 4,194,304
// total = 39,346,176 float-slots = 157.4 MB (== round-1 proven footprint)

// ---------------- trig tables (fp16, both orientations) ----------------
__global__ void k_tab(unsigned short* __restrict__ tabB, unsigned short* __restrict__ tabT){
    int t = blockIdx.x*256 + threadIdx.x;        // 64*4096
    int m2 = t >> 12, n = t & 4095;
    int m = m2 & 31;
    int r = (m*n) & 4095;
    double a = (double)r * (6.283185307179586476925286766559 / 4096.0);
    float v = (m2 >= 32) ? (float)sin(a) : (float)cos(a);
    tabB[(size_t)m2*4096 + n] = f2h(v);
    tabT[(size_t)n*64 + m2]   = f2h(v * 0.015625f);   // 1/64 folded in (exact pow2)
}

// ---------------- conditioning MLP ----------------
__global__ __launch_bounds__(64) void k_cond(const float* __restrict__ instp,
        const float* __restrict__ w1, const float* __restrict__ b1,
        const float* __restrict__ w2, const float* __restrict__ b2,
        float* __restrict__ cond){
    int b = blockIdx.x, tid = threadIdx.x;
    __shared__ float ipl[8];
    __shared__ float tl[64];
    if (tid < 8) ipl[tid] = instp[b*8 + tid];
    __syncthreads();
    float s = b1[tid];
    #pragma unroll
    for (int k = 0; k < 8; ++k) s = fmaf(ipl[k], w1[k*64 + tid], s);
    tl[tid] = gelu_f(s);
    __syncthreads();
    float c = b2[tid];
    #pragma unroll 8
    for (int j = 0; j < 64; ++j) c = fmaf(tl[j], w2[j*64 + tid], c);
    cond[b*64 + tid] = c;
}

// ---------------- lift + interp + cond -> xh (fp16) ----------------
__global__ __launch_bounds__(256) void k_lift(const float* __restrict__ z,
        const float* __restrict__ lw, const float* __restrict__ lb,
        const float* __restrict__ cond, unsigned short* __restrict__ xh){
    int bid = blockIdx.x;
    int b = bid >> 6, wc = bid & 63;
    int tid = threadIdx.x;
    __shared__ float zl[128];
    __shared__ float x0[64];
    if (tid < 128) zl[tid] = z[b*128 + tid];
    __syncthreads();
    if (tid < 64){
        float s = lb[wc*64 + tid];
        #pragma unroll 4
        for (int d = 0; d < 128; ++d) s = fmaf(zl[d], lw[d*4096 + wc*64 + tid], s);
        x0[tid] = s + cond[b*64 + wc];   // cond add commutes with interp (weights sum to 1)
    }
    __syncthreads();
    unsigned short* xrow = xh + (size_t)(b*64 + wc)*4096;
    #pragma unroll
    for (int r = 0; r < 16; ++r){
        int n = r*256 + tid;
        float src = (n + 0.5f)*0.015625f - 0.5f;
        src = fminf(fmaxf(src, 0.0f), 63.0f);
        int i0 = (int)src;
        int i1 = (i0 + 1 > 63) ? 63 : (i0 + 1);
        float w = src - (float)i0;
        xrow[n] = f2h(x0[i0] + w*(x0[i1] - x0[i0]));
    }
}

// ---------------- prep: norm+gelu -> x, transpose-store xT, forward-DFT ----------------
// grid (b=128, ng=8), 256 thr. Per iter: [64 co][64 n] tile through swizzled LDS.
template<int NORM, int DODFT>
__global__ __launch_bounds__(256) void k_prep(
        const unsigned short* __restrict__ xhp, const float* __restrict__ stats,
        const unsigned short* __restrict__ tabB, unsigned short* __restrict__ xT,
        float* __restrict__ dftp)
{
    int b = blockIdx.x, ng = blockIdx.y;
    int t = threadIdx.x;
    int w = t >> 6, lane = t & 63;
    int lrow = lane & 15, g = lane >> 4;
    __shared__ __align__(16) unsigned short xl[4096];   // [64 co][64 n], XOR-swizzled
    int co = t >> 2, nq = t & 3;
    float mu = 0.f, rs = 1.f;
    if (NORM){ mu = stats[(b*64+co)*2]; rs = stats[(b*64+co)*2+1]; }
    fx4 acc[4];
    #pragma unroll
    for (int i = 0; i < 4; ++i) acc[i] = (fx4){0.f,0.f,0.f,0.f};

    const unsigned short* hrow = xhp + ((size_t)(b*64+co))*4096 + ng*512 + nq*16;
    unsigned short* xtbase = xT + ((size_t)b*4096 + (size_t)ng*512)*64;

    for (int it = 0; it < 8; ++it){
        int n0 = ng*512 + it*64;
        uint4 hA = *(const uint4*)(hrow + it*64);
        uint4 hB = *(const uint4*)(hrow + it*64 + 8);
        unsigned int pk[8];
        if (NORM){
            unsigned int hu[8] = {hA.x,hA.y,hA.z,hA.w,hB.x,hB.y,hB.z,hB.w};
            #pragma unroll
            for (int i = 0; i < 8; ++i){
                float f0 = h2f((unsigned short)(hu[i] & 0xFFFFu));
                float f1 = h2f((unsigned short)(hu[i] >> 16));
                f0 = gelu_f((f0 - mu)*rs);
                f1 = gelu_f((f1 - mu)*rs);
                pk[i] = (unsigned int)f2h(f0) | ((unsigned int)f2h(f1) << 16);
            }
        } else {
            pk[0]=hA.x; pk[1]=hA.y; pk[2]=hA.z; pk[3]=hA.w;
            pk[4]=hB.x; pk[5]=hB.y; pk[6]=hB.z; pk[7]=hB.w;
        }
        unsigned int base = (unsigned int)co*128 + (unsigned int)nq*32;
        unsigned int sw = (unsigned int)((co & 7) << 4);
        *(uint4*)((char*)xl + ((base +  0) ^ sw)) = make_uint4(pk[0],pk[1],pk[2],pk[3]);
        *(uint4*)((char*)xl + ((base + 16) ^ sw)) = make_uint4(pk[4],pk[5],pk[6],pk[7]);
        __syncthreads();

        if (DODFT){
            int m0 = w*16;
            #pragma unroll
            for (int ks = 0; ks < 2; ++ks){
                int kk = ks*32 + g*8;
                half8 af = *(const half8*)(tabB + (size_t)(m0 + lrow)*4096 + n0 + kk);
                #pragma unroll
                for (int ct = 0; ct < 4; ++ct){
                    int row = ct*16 + lrow;
                    unsigned int ba = ((unsigned int)row*128 + (unsigned int)kk*2)
                                      ^ (unsigned int)((row & 7) << 4);
                    half8 bf = *(const half8*)((const char*)xl + ba);
                    acc[ct] = __builtin_amdgcn_mfma_f32_16x16x32_f16(af, bf, acc[ct], 0, 0, 0);
                }
            }
        }
        {   // transpose out: xT[b][n][co]
            int n = t & 63, coq = t >> 6;
            unsigned int opk[8];
            #pragma unroll
            for (int i = 0; i < 8; ++i){
                int r0 = coq*16 + 2*i, r1 = r0 + 1;
                unsigned int a0 = ((unsigned int)r0*128 + (unsigned int)n*2)
                                  ^ (unsigned int)((r0 & 7) << 4);
                unsigned int a1 = ((unsigned int)r1*128 + (unsigned int)n*2)
                                  ^ (unsigned int)((r1 & 7) << 4);
                unsigned short v0 = *(const unsigned short*)((const char*)xl + a0);
                unsigned short v1 = *(const unsigned short*)((const char*)xl + a1);
                opk[i] = (unsigned int)v0 | ((unsigned int)v1 << 16);
            }
            unsigned short* dst = xtbase + (size_t)(it*64 + n)*64 + coq*16;
            *(uint4*)dst       = make_uint4(opk[0],opk[1],opk[2],opk[3]);
            *(uint4*)(dst + 8) = make_uint4(opk[4],opk[5],opk[6],opk[7]);
        }
        __syncthreads();
    }
    if (DODFT){
        int m0 = w*16;
        #pragma unroll
        for (int ct = 0; ct < 4; ++ct){
            #pragma unroll
            for (int j = 0; j < 4; ++j){
                dftp[((size_t)(b*8+ng)*64 + m0 + g*4 + j)*64 + ct*16 + lrow] = acc[ct][j];
            }
        }
    }
}

// ---------------- reduce DFT K-slices -> mx ----------------
__global__ void k_dftred(const float* __restrict__ dftp, float* __restrict__ mx){
    int t = blockIdx.x*256 + threadIdx.x;   // 262144 = b*2048 + ci*32 + m
    int m  = t & 31;
    int ci = (t >> 5) & 63;
    int b  = t >> 11;
    float cs = 0.f, ss = 0.f;
    #pragma unroll
    for (int ng = 0; ng < 8; ++ng){
        size_t base = (size_t)(b*8+ng)*4096;           // *64*64
        cs += dftp[base + (size_t)m*64 + ci];
        ss += dftp[base + (size_t)(32+m)*64 + ci];
    }
    mx[(size_t)t*2]   = cs;
    mx[(size_t)t*2+1] = -ss;
}

// ---------------- spectral mix (fp32) ----------------
// ma scaled x64 vs true coeffs; 1/64 folded into tabT.
__global__ __launch_bounds__(64) void k_mix(const float* __restrict__ mx,
        const float* __restrict__ specw, float* __restrict__ ma, int l){
    int b = blockIdx.x, m = blockIdx.y;
    int tid = threadIdx.x;
    __shared__ float xr[64], xi[64];
    int mi = ((b*64 + tid)*32 + m)*2;
    xr[tid] = mx[mi]; xi[tid] = mx[mi+1];
    __syncthreads();
    float yr = 0.f, yi = 0.f;
    const float* wb = specw + (size_t)l*262144 + tid*64 + 2*m;
    #pragma unroll 4
    for (int ci = 0; ci < 64; ++ci){
        float wr  = wb[ci*4096];
        float wiv = wb[ci*4096 + 1];
        yr += xr[ci]*wr  - xi[ci]*wiv;
        yi += xr[ci]*wiv + xi[ci]*wr;
    }
    float sc = (m == 0 ? 1.f : 2.f) * 0.015625f;       // (1|2)/4096 * 64
    ma[(size_t)(b*64 + tid)*64 + m]      = sc*yr;
    ma[(size_t)(b*64 + tid)*64 + 32 + m] = -0.03125f*yi; // 2/4096*64
}

// ---------------- fused pointwise + iDFT (MFMA) -> h fp16 + stats partials ----------------
// grid (b=128, ntg=16). H(64x256) = A(64x128) @ B(128x256); B rows from xT / tabT directly.
__global__ __launch_bounds__(256) void k_pass3(
        const unsigned short* __restrict__ xT, const unsigned short* __restrict__ tabT,
        const float* __restrict__ pww, const float* __restrict__ pwb,
        const float* __restrict__ ma, unsigned short* __restrict__ xh,
        float* __restrict__ part, int lay)
{
    int b = blockIdx.x, ntg = blockIdx.y;
    int n0 = ntg*256;
    int t = threadIdx.x, w = t >> 6, lane = t & 63;
    int lrow = lane & 15, g = lane >> 4;

    half8 A[4][4];
    #pragma unroll
    for (int ct = 0; ct < 4; ++ct){
        int co = ct*16 + lrow;
        #pragma unroll
        for (int ks = 0; ks < 4; ++ks){
            int k = ks*32 + g*8;
            const float* src = (k < 64) ? (pww + ((size_t)lay*64 + co)*64 + k)
                                        : (ma  + ((size_t)b*64 + co)*64 + (k - 64));
            A[ct][ks] = cvt8(*(const float4*)src, *(const float4*)(src + 4));
        }
    }
    fx4 acc[4][4];
    #pragma unroll
    for (int i = 0; i < 4; ++i)
        #pragma unroll
        for (int j = 0; j < 4; ++j) acc[i][j] = (fx4){0.f,0.f,0.f,0.f};

    #pragma unroll
    for (int ks = 0; ks < 4; ++ks){
        int k = ks*32 + g*8;
        #pragma unroll
        for (int ntl = 0; ntl < 4; ++ntl){
            int n = n0 + (w*4 + ntl)*16 + lrow;
            const unsigned short* bs = (k < 64) ? (xT + ((size_t)b*4096 + n)*64 + k)
                                                : (tabT + (size_t)n*64 + (k - 64));
            half8 bf = *(const half8*)bs;
            #pragma unroll
            for (int ct = 0; ct < 4; ++ct)
                acc[ct][ntl] = __builtin_amdgcn_mfma_f32_16x16x32_f16(A[ct][ks], bf, acc[ct][ntl], 0, 0, 0);
        }
    }
    // epilogue: +bias, fp16 store, stats partials
    __shared__ float sred[2][4][64];
    #pragma unroll
    for (int ct = 0; ct < 4; ++ct){
        #pragma unroll
        for (int j = 0; j < 4; ++j){
            int co = ct*16 + g*4 + j;
            float pb = pwb[lay*64 + co];
            unsigned short* hr = xh + ((size_t)(b*64+co))*4096;
            float s = 0.f, q = 0.f;
            #pragma unroll
            for (int ntl = 0; ntl < 4; ++ntl){
                int n = n0 + (w*4+ntl)*16 + lrow;
                float h = acc[ct][ntl][j] + pb;
                hr[n] = f2h(h);
                s += h; q = fmaf(h, h, q);
            }
            #pragma unroll
            for (int e = 1; e < 16; e <<= 1){ s += __shfl_xor(s, e); q += __shfl_xor(q, e); }
            if (lrow == 0){
                sred[0][w][co] = s;
                sred[1][w][co] = q;
            }
        }
    }
    __syncthreads();
    if (t < 64){
        float S = 0.f, Q = 0.f;
        #pragma unroll
        for (int ww = 0; ww < 4; ++ww){ S += sred[0][ww][t]; Q += sred[1][ww][t]; }
        part[((size_t)(b*64+t)*16 + ntg)*2]     = S;
        part[((size_t)(b*64+t)*16 + ntg)*2 + 1] = Q;
    }
}

// ---------------- stats reduce ----------------
__global__ void k_stats(const float* __restrict__ part, float* __restrict__ stats){
    int t = blockIdx.x*256 + threadIdx.x;    // 8192 = b*64+co
    if (t >= 8192) return;
    float S = 0.f, Q = 0.f;
    #pragma unroll
    for (int i = 0; i < 16; ++i){ S += part[(t*16+i)*2]; Q += part[(t*16+i)*2+1]; }
    float mu  = S * (1.f/4096.f);
    float var = Q * (1.f/4096.f) - mu*mu;
    stats[t*2]   = mu;
    stats[t*2+1] = rsqrtf(var + 1e-5f);
}

// ---------------- projection head (MFMA) ----------------
// grid (b=128, ntg=32). H1(128x128) = W1(128x64)@xT-tile; out = w2.gelu(H1+b1)+b2
__global__ __launch_bounds__(256) void k_proj(
        const unsigned short* __restrict__ xT, const float* __restrict__ w1,
        const float* __restrict__ b1, const float* __restrict__ w2,
        const float* __restrict__ b2, float* __restrict__ out)
{
    int b = blockIdx.x, ntg = blockIdx.y;
    int n0 = ntg*128;
    int t = threadIdx.x, w = t >> 6, lane = t & 63;
    int lrow = lane & 15, g = lane >> 4;

    half8 A[8][2];
    #pragma unroll
    for (int ot = 0; ot < 8; ++ot){
        int o2 = ot*16 + lrow;
        #pragma unroll
        for (int ks = 0; ks < 2; ++ks){
            int k = ks*32 + g*8;
            const float* src = w1 + (size_t)o2*64 + k;
            A[ot][ks] = cvt8(*(const float4*)src, *(const float4*)(src + 4));
        }
    }
    fx4 acc[8][2];
    #pragma unroll
    for (int i = 0; i < 8; ++i){ acc[i][0] = (fx4){0.f,0.f,0.f,0.f}; acc[i][1] = (fx4){0.f,0.f,0.f,0.f}; }

    #pragma unroll
    for (int ks = 0; ks < 2; ++ks){
        #pragma unroll
        for (int ntl = 0; ntl < 2; ++ntl){
            int n = n0 + (w*2 + ntl)*16 + lrow;
            half8 bf = *(const half8*)(xT + ((size_t)b*4096 + n)*64 + ks*32 + g*8);
            #pragma unroll
            for (int ot = 0; ot < 8; ++ot)
                acc[ot][ntl] = __builtin_amdgcn_mfma_f32_16x16x32_f16(A[ot][ks], bf, acc[ot][ntl], 0, 0, 0);
        }
    }
    float p0 = 0.f, p1 = 0.f;
    #pragma unroll
    for (int ot = 0; ot < 8; ++ot){
        #pragma unroll
        for (int j = 0; j < 4; ++j){
            int o2 = ot*16 + g*4 + j;
            float bb = b1[o2], wv = w2[o2];
            p0 = fmaf(wv, gelu_f(acc[ot][0][j] + bb), p0);
            p1 = fmaf(wv, gelu_f(acc[ot][1][j] + bb), p1);
        }
    }
    p0 += __shfl_xor(p0, 16); p0 += __shfl_xor(p0, 32);
    p1 += __shfl_xor(p1, 16); p1 += __shfl_xor(p1, 32);
    if (lane < 16){
        float bias = b2[0];
        out[(size_t)b*4096 + n0 + (w*2+0)*16 + lane] = p0 + bias;
        out[(size_t)b*4096 + n0 + (w*2+1)*16 + lane] = p1 + bias;
    }
}

// ---------------- launch ----------------
extern "C" void kernel_launch(void* const* d_in, const int* in_sizes, int n_in,
                              void* d_out, int out_size, void* d_ws, size_t ws_size,
                              hipStream_t stream) {
    (void)in_sizes; (void)n_in; (void)out_size; (void)ws_size;
    const float* z      = (const float*)d_in[0];
    const float* instp  = (const float*)d_in[1];
    const float* lift_w = (const float*)d_in[2];
    const float* lift_b = (const float*)d_in[3];
    const float* iw1    = (const float*)d_in[4];
    const float* ib1    = (const float*)d_in[5];
    const float* iw2    = (const float*)d_in[6];
    const float* ib2    = (const float*)d_in[7];
    const float* specw  = (const float*)d_in[8];
    const float* pww    = (const float*)d_in[9];
    const float* pwb    = (const float*)d_in[10];
    const float* pj1w   = (const float*)d_in[11];
    const float* pj1b   = (const float*)d_in[12];
    const float* pj2w   = (const float*)d_in[13];
    const float* pj2b   = (const float*)d_in[14];

    float* ws = (float*)d_ws;
    unsigned short* xh   = (unsigned short*)(ws + OFF_XH);
    unsigned short* xT   = (unsigned short*)(ws + OFF_XT);
    unsigned short* tabB = (unsigned short*)(ws + OFF_TABB);
    unsigned short* tabT = (unsigned short*)(ws + OFF_TABT);
    float* mx    = ws + OFF_MX;
    float* ma    = ws + OFF_MA;
    float* cond  = ws + OFF_COND;
    float* part  = ws + OFF_PART;
    float* stats = ws + OFF_STATS;
    float* dftp  = ws + OFF_DFTP;
    float* out   = (float*)d_out;

    k_tab <<<dim3(1024), dim3(256), 0, stream>>>(tabB, tabT);
    k_cond<<<dim3(128),  dim3(64),  0, stream>>>(instp, iw1, ib1, iw2, ib2, cond);
    k_lift<<<dim3(8192), dim3(256), 0, stream>>>(z, lift_w, lift_b, cond, xh);

    for (int l = 0; l < 4; ++l){
        if (l == 0)
            k_prep<0,1><<<dim3(128,8), dim3(256), 0, stream>>>(xh, stats, tabB, xT, dftp);
        else
            k_prep<1,1><<<dim3(128,8), dim3(256), 0, stream>>>(xh, stats, tabB, xT, dftp);
        k_dftred<<<dim3(1024),    dim3(256), 0, stream>>>(dftp, mx);
        k_mix   <<<dim3(128,32),  dim3(64),  0, stream>>>(mx, specw, ma, l);
        k_pass3 <<<dim3(128,16),  dim3(256), 0, stream>>>(xT, tabT, pww, pwb, ma, xh, part, l);
        k_stats <<<dim3(32),      dim3(256), 0, stream>>>(part, stats);
    }
    k_prep<1,0><<<dim3(128,8),  dim3(256), 0, stream>>>(xh, stats, tabB, xT, dftp);
    k_proj    <<<dim3(128,32),  dim3(256), 0, stream>>>(xT, pj1w, pj1b, pj2w, pj2b, out);
}

// Round 5
// 629.698 us; speedup vs baseline: 2.6860x; 1.5418x over previous
//
#include <hip/hip_runtime.h>
#include <math.h>

// B=128, W=64, L=4096, MODES=32, N_LAYERS=4

typedef _Float16 half8 __attribute__((ext_vector_type(8)));  // 8 fp16 (4 VGPR)
typedef __attribute__((ext_vector_type(4))) float fx4;       // MFMA f32 acc

// fast gelu: Abramowitz-Stegun 7.1.26 erf (max abs err 1.5e-7)
__device__ __forceinline__ float gelu_f(float x){
    float az = fabsf(x) * 0.70710678118654752f;
    float t  = 1.0f / fmaf(0.3275911f, az, 1.0f);
    float p  = t*fmaf(t, fmaf(t, fmaf(t, fmaf(t, 1.061405429f, -1.453152027f),
                      1.421413741f), -0.284496736f), 0.254829592f);
    float er = 1.0f - p * __expf(-az*az);     // erf(az), az >= 0
    float s  = (x >= 0.f) ? er : -er;
    return 0.5f * x * (1.0f + s);
}
__device__ __forceinline__ unsigned short f2h(float f){
    union { _Float16 h; unsigned short u; } c;
    c.h = (_Float16)f;
    return c.u;
}
__device__ __forceinline__ float h2f(unsigned short u){
    union { unsigned short u; _Float16 h; } c;
    c.u = u;
    return (float)c.h;
}

// ---------------- workspace layout (float-slot offsets) ----------------
// xh   : fp16 [128][64][4096]   h / x0 (channel-major)
// xT   : fp16 [128][4096][64]   normalized x, position-major (MFMA k=ci)
// tabB : fp16 [64][4096]        rows 0-31 cos, 32-63 sin (unscaled, fwd DFT)
// tabT : fp16 [4096][64]        transpose, scaled 1/64 (iDFT)
// mx   : f32  [b][32 m][64 ci][2]
// mah  : fp16 [b][co][64]       iDFT coeffs x64 (32 cos | 32 sin)
// pwwh : fp16 [4][64][64]       pw_w converted
// w1h  : fp16 [128][64]         proj_w1 converted
// cond : f32  [b][64]
// part : f32  [b][co][16][2]
// stats: f32  [b][co][2]
// dftp : f32  [b][ng=8][64 m2][64 ci]
static const size_t OFF_XH    = 0;                       // 16,777,216
static const size_t OFF_XT    = 16777216;                // 16,777,216
static const size_t OFF_TABB  = 33554432;                // 131,072
static const size_t OFF_TABT  = 33685504;                // 131,072
static const size_t OFF_MX    = 33816576;                // 524,288
static const size_t OFF_MAH   = 34340864;                // 262,144 (fp16 x 524288)
static const size_t OFF_PWWH  = 34603008;                // 8,192   (fp16 x 16384)
static const size_t OFF_W1H   = 34611200;                // 4,096   (fp16 x 8192)
static const size_t OFF_COND  = 34865152;                // 8,192
static const size_t OFF_PART  = 34873344;                // 262,144
static const size_t OFF_STATS = 35135488;                // 16,384
static const size_t OFF_DFTP  = 35151872;                // 4,194,304
// total = 39,346,176 float-slots = 157.4 MB (proven footprint)

// ---------------- trig tables + weight fp16 conversion ----------------
__global__ void k_tab(unsigned short* __restrict__ tabB, unsigned short* __restrict__ tabT,
                      const float* __restrict__ pww, unsigned short* __restrict__ pwwh,
                      const float* __restrict__ pj1w, unsigned short* __restrict__ w1h){
    int t = blockIdx.x*256 + threadIdx.x;        // 64*4096 = 262144
    if (t < 16384) pwwh[t] = f2h(pww[t]);
    if (t < 8192)  w1h[t]  = f2h(pj1w[t]);
    int m2 = t >> 12, n = t & 4095;
    int m = m2 & 31;
    int r = (m*n) & 4095;
    double a = (double)r * (6.283185307179586476925286766559 / 4096.0);
    float v = (m2 >= 32) ? (float)sin(a) : (float)cos(a);
    tabB[(size_t)m2*4096 + n] = f2h(v);
    tabT[(size_t)n*64 + m2]   = f2h(v * 0.015625f);   // 1/64 folded (exact pow2)
}

// ---------------- conditioning MLP ----------------
__global__ __launch_bounds__(64) void k_cond(const float* __restrict__ instp,
        const float* __restrict__ w1, const float* __restrict__ b1,
        const float* __restrict__ w2, const float* __restrict__ b2,
        float* __restrict__ cond){
    int b = blockIdx.x, tid = threadIdx.x;
    __shared__ float ipl[8];
    __shared__ float tl[64];
    if (tid < 8) ipl[tid] = instp[b*8 + tid];
    __syncthreads();
    float s = b1[tid];
    #pragma unroll
    for (int k = 0; k < 8; ++k) s = fmaf(ipl[k], w1[k*64 + tid], s);
    tl[tid] = gelu_f(s);
    __syncthreads();
    float c = b2[tid];
    #pragma unroll 8
    for (int j = 0; j < 64; ++j) c = fmaf(tl[j], w2[j*64 + tid], c);
    cond[b*64 + tid] = c;
}

// ---------------- lift + interp + cond -> xh (fp16) ----------------
__global__ __launch_bounds__(256) void k_lift(const float* __restrict__ z,
        const float* __restrict__ lw, const float* __restrict__ lb,
        const float* __restrict__ cond, unsigned short* __restrict__ xh){
    int bid = blockIdx.x;
    int b = bid >> 6, wc = bid & 63;
    int tid = threadIdx.x;
    int co = tid & 63, kq = tid >> 6;
    __shared__ float zl[128];
    __shared__ float red[4][64];
    __shared__ float x0[64];
    if (tid < 128) zl[tid] = z[b*128 + tid];
    __syncthreads();
    float s = 0.f;
    #pragma unroll 8
    for (int dd = 0; dd < 32; ++dd){
        int d = kq*32 + dd;
        s = fmaf(zl[d], lw[(size_t)d*4096 + wc*64 + co], s);
    }
    red[kq][co] = s;
    __syncthreads();
    if (tid < 64){
        // cond is per-CHANNEL (wc), broadcast over lift positions (tid)
        x0[tid] = red[0][tid] + red[1][tid] + red[2][tid] + red[3][tid]
                + lb[wc*64 + tid] + cond[b*64 + wc];
    }
    __syncthreads();
    unsigned short* xrow = xh + (size_t)(b*64 + wc)*4096;
    #pragma unroll
    for (int r = 0; r < 16; ++r){
        int n = r*256 + tid;
        float src = (n + 0.5f)*0.015625f - 0.5f;
        src = fminf(fmaxf(src, 0.0f), 63.0f);
        int i0 = (int)src;
        int i1 = (i0 + 1 > 63) ? 63 : (i0 + 1);
        float w = src - (float)i0;
        xrow[n] = f2h(x0[i0] + w*(x0[i1] - x0[i0]));
    }
}

// ---------------- prep: norm+gelu -> x, transpose-store xT, forward-DFT ----------------
template<int NORM, int DODFT>
__global__ __launch_bounds__(256) void k_prep(
        const unsigned short* __restrict__ xhp, const float* __restrict__ stats,
        const unsigned short* __restrict__ tabB, unsigned short* __restrict__ xT,
        float* __restrict__ dftp)
{
    int b = blockIdx.x, ng = blockIdx.y;
    int t = threadIdx.x;
    int w = t >> 6, lane = t & 63;
    int lrow = lane & 15, g = lane >> 4;
    __shared__ __align__(16) unsigned short xl[4096];   // [64 co][64 n], XOR-swizzled
    int co = t >> 2, nq = t & 3;
    float mu = 0.f, rs = 1.f;
    if (NORM){ mu = stats[(b*64+co)*2]; rs = stats[(b*64+co)*2+1]; }
    fx4 acc[4];
    #pragma unroll
    for (int i = 0; i < 4; ++i) acc[i] = (fx4){0.f,0.f,0.f,0.f};

    const unsigned short* hrow = xhp + ((size_t)(b*64+co))*4096 + ng*512 + nq*16;
    unsigned short* xtbase = xT + ((size_t)b*4096 + (size_t)ng*512)*64;

    for (int it = 0; it < 8; ++it){
        int n0 = ng*512 + it*64;
        uint4 hA = *(const uint4*)(hrow + it*64);
        uint4 hB = *(const uint4*)(hrow + it*64 + 8);
        unsigned int pk[8];
        if (NORM){
            unsigned int hu[8] = {hA.x,hA.y,hA.z,hA.w,hB.x,hB.y,hB.z,hB.w};
            #pragma unroll
            for (int i = 0; i < 8; ++i){
                float f0 = h2f((unsigned short)(hu[i] & 0xFFFFu));
                float f1 = h2f((unsigned short)(hu[i] >> 16));
                f0 = gelu_f((f0 - mu)*rs);
                f1 = gelu_f((f1 - mu)*rs);
                pk[i] = (unsigned int)f2h(f0) | ((unsigned int)f2h(f1) << 16);
            }
        } else {
            pk[0]=hA.x; pk[1]=hA.y; pk[2]=hA.z; pk[3]=hA.w;
            pk[4]=hB.x; pk[5]=hB.y; pk[6]=hB.z; pk[7]=hB.w;
        }
        unsigned int base = (unsigned int)co*128 + (unsigned int)nq*32;
        unsigned int sw = (unsigned int)((co & 7) << 4);
        *(uint4*)((char*)xl + ((base +  0) ^ sw)) = make_uint4(pk[0],pk[1],pk[2],pk[3]);
        *(uint4*)((char*)xl + ((base + 16) ^ sw)) = make_uint4(pk[4],pk[5],pk[6],pk[7]);
        __syncthreads();

        if (DODFT){
            int m0 = w*16;
            #pragma unroll
            for (int ks = 0; ks < 2; ++ks){
                int kk = ks*32 + g*8;
                half8 af = *(const half8*)(tabB + (size_t)(m0 + lrow)*4096 + n0 + kk);
                #pragma unroll
                for (int ct = 0; ct < 4; ++ct){
                    int row = ct*16 + lrow;
                    unsigned int ba = ((unsigned int)row*128 + (unsigned int)kk*2)
                                      ^ (unsigned int)((row & 7) << 4);
                    half8 bf = *(const half8*)((const char*)xl + ba);
                    acc[ct] = __builtin_amdgcn_mfma_f32_16x16x32_f16(af, bf, acc[ct], 0, 0, 0);
                }
            }
        }
        {   // transpose out: xT[b][n][co]
            int n = t & 63, coq = t >> 6;
            unsigned int opk[8];
            #pragma unroll
            for (int i = 0; i < 8; ++i){
                int r0 = coq*16 + 2*i, r1 = r0 + 1;
                unsigned int a0 = ((unsigned int)r0*128 + (unsigned int)n*2)
                                  ^ (unsigned int)((r0 & 7) << 4);
                unsigned int a1 = ((unsigned int)r1*128 + (unsigned int)n*2)
                                  ^ (unsigned int)((r1 & 7) << 4);
                unsigned short v0 = *(const unsigned short*)((const char*)xl + a0);
                unsigned short v1 = *(const unsigned short*)((const char*)xl + a1);
                opk[i] = (unsigned int)v0 | ((unsigned int)v1 << 16);
            }
            unsigned short* dst = xtbase + (size_t)(it*64 + n)*64 + coq*16;
            *(uint4*)dst       = make_uint4(opk[0],opk[1],opk[2],opk[3]);
            *(uint4*)(dst + 8) = make_uint4(opk[4],opk[5],opk[6],opk[7]);
        }
        __syncthreads();
    }
    if (DODFT){
        int m0 = w*16;
        #pragma unroll
        for (int ct = 0; ct < 4; ++ct){
            #pragma unroll
            for (int j = 0; j < 4; ++j){
                dftp[((size_t)(b*8+ng)*64 + m0 + g*4 + j)*64 + ct*16 + lrow] = acc[ct][j];
            }
        }
    }
}

// ---------------- reduce DFT K-slices -> mx [b][m][ci][2], coalesced ----------------
__global__ void k_dftred(const float* __restrict__ dftp, float* __restrict__ mx){
    int t = blockIdx.x*256 + threadIdx.x;   // 262144 = b*2048 + m*64 + ci
    int ci = t & 63;
    int m  = (t >> 6) & 31;
    int b  = t >> 11;
    float cs = 0.f, ss = 0.f;
    #pragma unroll
    for (int ng = 0; ng < 8; ++ng){
        size_t base = (size_t)(b*8+ng)*4096;
        cs += dftp[base + (size_t)m*64 + ci];
        ss += dftp[base + (size_t)(32+m)*64 + ci];
    }
    ((float2*)mx)[t] = make_float2(cs, -ss);
}

// ---------------- spectral mix (fp32 math, fp16 out), coalesced specw ----------------
// grid (128 b), 256 thr: thread (co = t>>2, mq = t&3) handles 8 modes.
__global__ __launch_bounds__(256) void k_mix(const float* __restrict__ mx,
        const float* __restrict__ specw, unsigned short* __restrict__ mah, int l){
    int b = blockIdx.x, t = threadIdx.x;
    int co = t >> 2, mq = t & 3;
    __shared__ float xm[4096];               // [32 m][64 ci][2]
    const float* xb = mx + (size_t)b*4096;
    #pragma unroll
    for (int i = 0; i < 4; ++i){
        int idx = (i*256 + t)*4;
        *(float4*)(xm + idx) = *(const float4*)(xb + idx);
    }
    __syncthreads();
    float yr[8] = {0,0,0,0,0,0,0,0}, yi[8] = {0,0,0,0,0,0,0,0};
    const float* wbase = specw + (size_t)(l*64)*4096 + co*64 + mq*16;   // + ci*4096
    for (int ci = 0; ci < 64; ++ci){
        const float* wp = wbase + (size_t)ci*4096;
        float4 w0 = *(const float4*)(wp);
        float4 w1v = *(const float4*)(wp + 4);
        float4 w2v = *(const float4*)(wp + 8);
        float4 w3v = *(const float4*)(wp + 12);
        float wr[8] = {w0.x,w0.z,w1v.x,w1v.z,w2v.x,w2v.z,w3v.x,w3v.z};
        float wi[8] = {w0.y,w0.w,w1v.y,w1v.w,w2v.y,w2v.w,w3v.y,w3v.w};
        #pragma unroll
        for (int mm = 0; mm < 8; ++mm){
            int m = mq*8 + mm;
            float2 x = *(const float2*)(xm + (m*64 + ci)*2);
            yr[mm] = fmaf(x.x, wr[mm], fmaf(-x.y, wi[mm], yr[mm]));
            yi[mm] = fmaf(x.x, wi[mm], fmaf( x.y, wr[mm], yi[mm]));
        }
    }
    unsigned short* mb = mah + (size_t)(b*64 + co)*64;
    #pragma unroll
    for (int mm = 0; mm < 8; ++mm){
        int m = mq*8 + mm;
        float sc = (m == 0) ? 0.015625f : 0.03125f;   // (1|2)/4096 * 64
        mb[m]      = f2h(sc * yr[mm]);
        mb[32 + m] = f2h(-0.03125f * yi[mm]);
    }
}

// ---------------- fused pointwise + iDFT (MFMA) -> h fp16 + stats partials ----------------
__global__ __launch_bounds__(256) void k_pass3(
        const unsigned short* __restrict__ xT, const unsigned short* __restrict__ tabT,
        const unsigned short* __restrict__ pwwh, const float* __restrict__ pwb,
        const unsigned short* __restrict__ mah, unsigned short* __restrict__ xh,
        float* __restrict__ part, int lay)
{
    int b = blockIdx.x, ntg = blockIdx.y;
    int n0 = ntg*256;
    int t = threadIdx.x, w = t >> 6, lane = t & 63;
    int lrow = lane & 15, g = lane >> 4;

    half8 A[4][4];
    #pragma unroll
    for (int ct = 0; ct < 4; ++ct){
        int co = ct*16 + lrow;
        #pragma unroll
        for (int ks = 0; ks < 4; ++ks){
            int k = ks*32 + g*8;
            const unsigned short* src = (k < 64)
                ? (pwwh + ((size_t)lay*64 + co)*64 + k)
                : (mah  + ((size_t)b*64 + co)*64 + (k - 64));
            A[ct][ks] = *(const half8*)src;
        }
    }
    fx4 acc[4][4];
    #pragma unroll
    for (int i = 0; i < 4; ++i)
        #pragma unroll
        for (int j = 0; j < 4; ++j) acc[i][j] = (fx4){0.f,0.f,0.f,0.f};

    #pragma unroll
    for (int ks = 0; ks < 4; ++ks){
        int k = ks*32 + g*8;
        #pragma unroll
        for (int ntl = 0; ntl < 4; ++ntl){
            int n = n0 + (w*4 + ntl)*16 + lrow;
            const unsigned short* bs = (k < 64) ? (xT + ((size_t)b*4096 + n)*64 + k)
                                                : (tabT + (size_t)n*64 + (k - 64));
            half8 bf = *(const half8*)bs;
            #pragma unroll
            for (int ct = 0; ct < 4; ++ct)
                acc[ct][ntl] = __builtin_amdgcn_mfma_f32_16x16x32_f16(A[ct][ks], bf, acc[ct][ntl], 0, 0, 0);
        }
    }
    __shared__ float sred[2][4][64];
    #pragma unroll
    for (int ct = 0; ct < 4; ++ct){
        #pragma unroll
        for (int j = 0; j < 4; ++j){
            int co = ct*16 + g*4 + j;
            float pb = pwb[lay*64 + co];
            unsigned short* hr = xh + ((size_t)(b*64+co))*4096;
            float s = 0.f, q = 0.f;
            #pragma unroll
            for (int ntl = 0; ntl < 4; ++ntl){
                int n = n0 + (w*4+ntl)*16 + lrow;
                float h = acc[ct][ntl][j] + pb;
                hr[n] = f2h(h);
                s += h; q = fmaf(h, h, q);
            }
            #pragma unroll
            for (int e = 1; e < 16; e <<= 1){ s += __shfl_xor(s, e); q += __shfl_xor(q, e); }
            if (lrow == 0){
                sred[0][w][co] = s;
                sred[1][w][co] = q;
            }
        }
    }
    __syncthreads();
    if (t < 64){
        float S = 0.f, Q = 0.f;
        #pragma unroll
        for (int ww = 0; ww < 4; ++ww){ S += sred[0][ww][t]; Q += sred[1][ww][t]; }
        part[((size_t)(b*64+t)*16 + ntg)*2]     = S;
        part[((size_t)(b*64+t)*16 + ntg)*2 + 1] = Q;
    }
}

// ---------------- stats reduce ----------------
__global__ void k_stats(const float* __restrict__ part, float* __restrict__ stats){
    int t = blockIdx.x*256 + threadIdx.x;    // 8192 = b*64+co
    if (t >= 8192) return;
    float S = 0.f, Q = 0.f;
    #pragma unroll
    for (int i = 0; i < 16; ++i){ S += part[(t*16+i)*2]; Q += part[(t*16+i)*2+1]; }
    float mu  = S * (1.f/4096.f);
    float var = Q * (1.f/4096.f) - mu*mu;
    stats[t*2]   = mu;
    stats[t*2+1] = rsqrtf(var + 1e-5f);
}

// ---------------- projection head (MFMA, 8 waves, o2-split) ----------------
__global__ __launch_bounds__(512) void k_proj(
        const unsigned short* __restrict__ xT, const unsigned short* __restrict__ w1h,
        const float* __restrict__ b1, const float* __restrict__ w2,
        const float* __restrict__ b2, float* __restrict__ out)
{
    int b = blockIdx.x, ntg = blockIdx.y;
    int t = threadIdx.x, w = t >> 6, lane = t & 63;
    int lrow = lane & 15, g = lane >> 4;
    int o2h = w & 1, nq = w >> 1;
    int n0 = ntg*128 + nq*32;

    half8 A[4][2];
    #pragma unroll
    for (int ot = 0; ot < 4; ++ot)
        #pragma unroll
        for (int ks = 0; ks < 2; ++ks)
            A[ot][ks] = *(const half8*)(w1h + (size_t)(o2h*64 + ot*16 + lrow)*64 + ks*32 + g*8);

    fx4 acc[4][2];
    #pragma unroll
    for (int i = 0; i < 4; ++i){ acc[i][0] = (fx4){0.f,0.f,0.f,0.f}; acc[i][1] = (fx4){0.f,0.f,0.f,0.f}; }

    #pragma unroll
    for (int ks = 0; ks < 2; ++ks){
        #pragma unroll
        for (int ntl = 0; ntl < 2; ++ntl){
            int n = n0 + ntl*16 + lrow;
            half8 bf = *(const half8*)(xT + ((size_t)b*4096 + n)*64 + ks*32 + g*8);
            #pragma unroll
            for (int ot = 0; ot < 4; ++ot)
                acc[ot][ntl] = __builtin_amdgcn_mfma_f32_16x16x32_f16(A[ot][ks], bf, acc[ot][ntl], 0, 0, 0);
        }
    }
    float p0 = 0.f, p1 = 0.f;
    #pragma unroll
    for (int ot = 0; ot < 4; ++ot){
        #pragma unroll
        for (int j = 0; j < 4; ++j){
            int o2 = o2h*64 + ot*16 + g*4 + j;
            float bb = b1[o2], wv = w2[o2];
            p0 = fmaf(wv, gelu_f(acc[ot][0][j] + bb), p0);
            p1 = fmaf(wv, gelu_f(acc[ot][1][j] + bb), p1);
        }
    }
    p0 += __shfl_xor(p0, 16); p0 += __shfl_xor(p0, 32);
    p1 += __shfl_xor(p1, 16); p1 += __shfl_xor(p1, 32);
    __shared__ float sred[4][2][32];
    if (lane < 16){
        sred[nq][o2h][lane]      = p0;
        sred[nq][o2h][16 + lane] = p1;
    }
    __syncthreads();
    if (t < 128){
        int nqf = t >> 5, nl = t & 31;
        out[(size_t)b*4096 + ntg*128 + nqf*32 + nl] =
            sred[nqf][0][nl] + sred[nqf][1][nl] + b2[0];
    }
}

// ---------------- launch ----------------
extern "C" void kernel_launch(void* const* d_in, const int* in_sizes, int n_in,
                              void* d_out, int out_size, void* d_ws, size_t ws_size,
                              hipStream_t stream) {
    (void)in_sizes; (void)n_in; (void)out_size; (void)ws_size;
    const float* z      = (const float*)d_in[0];
    const float* instp  = (const float*)d_in[1];
    const float* lift_w = (const float*)d_in[2];
    const float* lift_b = (const float*)d_in[3];
    const float* iw1    = (const float*)d_in[4];
    const float* ib1    = (const float*)d_in[5];
    const float* iw2    = (const float*)d_in[6];
    const float* ib2    = (const float*)d_in[7];
    const float* specw  = (const float*)d_in[8];
    const float* pww    = (const float*)d_in[9];
    const float* pwb    = (const float*)d_in[10];
    const float* pj1w   = (const float*)d_in[11];
    const float* pj1b   = (const float*)d_in[12];
    const float* pj2w   = (const float*)d_in[13];
    const float* pj2b   = (const float*)d_in[14];

    float* ws = (float*)d_ws;
    unsigned short* xh   = (unsigned short*)(ws + OFF_XH);
    unsigned short* xT   = (unsigned short*)(ws + OFF_XT);
    unsigned short* tabB = (unsigned short*)(ws + OFF_TABB);
    unsigned short* tabT = (unsigned short*)(ws + OFF_TABT);
    unsigned short* mah  = (unsigned short*)(ws + OFF_MAH);
    unsigned short* pwwh = (unsigned short*)(ws + OFF_PWWH);
    unsigned short* w1h  = (unsigned short*)(ws + OFF_W1H);
    float* mx    = ws + OFF_MX;
    float* cond  = ws + OFF_COND;
    float* part  = ws + OFF_PART;
    float* stats = ws + OFF_STATS;
    float* dftp  = ws + OFF_DFTP;
    float* out   = (float*)d_out;

    k_tab <<<dim3(1024), dim3(256), 0, stream>>>(tabB, tabT, pww, pwwh, pj1w, w1h);
    k_cond<<<dim3(128),  dim3(64),  0, stream>>>(instp, iw1, ib1, iw2, ib2, cond);
    k_lift<<<dim3(8192), dim3(256), 0, stream>>>(z, lift_w, lift_b, cond, xh);

    for (int l = 0; l < 4; ++l){
        if (l == 0)
            k_prep<0,1><<<dim3(128,8), dim3(256), 0, stream>>>(xh, stats, tabB, xT, dftp);
        else
            k_prep<1,1><<<dim3(128,8), dim3(256), 0, stream>>>(xh, stats, tabB, xT, dftp);
        k_dftred<<<dim3(1024),   dim3(256), 0, stream>>>(dftp, mx);
        k_mix   <<<dim3(128),    dim3(256), 0, stream>>>(mx, specw, mah, l);
        k_pass3 <<<dim3(128,16), dim3(256), 0, stream>>>(xT, tabT, pwwh, pwb, mah, xh, part, l);
        k_stats <<<dim3(32),     dim3(256), 0, stream>>>(part, stats);
    }
    k_prep<1,0><<<dim3(128,8),  dim3(256), 0, stream>>>(xh, stats, tabB, xT, dftp);
    k_proj    <<<dim3(128,32),  dim3(512), 0, stream>>>(xT, w1h, pj1b, pj2w, pj2b, out);
}

// Round 6
// 605.646 us; speedup vs baseline: 2.7927x; 1.0397x over previous
//
#include <hip/hip_runtime.h>
#include <math.h>

// B=128, W=64, L=4096, MODES=32, N_LAYERS=4

typedef _Float16 half8 __attribute__((ext_vector_type(8)));  // 8 fp16 (4 VGPR)
typedef __attribute__((ext_vector_type(4))) float fx4;       // MFMA f32 acc

// fast gelu: tanh/sigmoid form, exp2-folded. gelu(x) ~= x * sigmoid(2y),
// 2y*log2e = x*(2.3022083 + 0.1029443*x^2). Max dev from exact-erf ~5e-4.
__device__ __forceinline__ float gelu_f(float x){
    float u = x*x;
    float a = x * fmaf(-0.1029443f, u, -2.3022083f);   // -2y*log2(e)
    float e = exp2f(a);                                 // e^{-2y}
    float r = __builtin_amdgcn_rcpf(1.0f + e);          // sigmoid(2y)
    return x * r;
}
__device__ __forceinline__ unsigned short f2h(float f){
    union { _Float16 h; unsigned short u; } c;
    c.h = (_Float16)f;
    return c.u;
}
__device__ __forceinline__ float h2f(unsigned short u){
    union { unsigned short u; _Float16 h; } c;
    c.u = u;
    return (float)c.h;
}

// ---------------- workspace layout (float-slot offsets) ----------------
// xh    : fp16 [128][64][4096]  h / x0 (channel-major)
// xT    : fp16 [128][4096][64]  normalized x, position-major
// tabB  : fp16 [64][4096]       rows 0-31 cos, 32-63 sin (fwd DFT)
// tabT  : fp16 [4096][64]       transpose, scaled 1/64 (iDFT)
// mah   : fp16 [b][co][64]      iDFT coeffs x64
// pwwh  : fp16 [4][64][64]
// w1h   : fp16 [128][64]
// cond  : f32  [b][64]
// statsr: f32  [b][co][2]       RAW (S, Q) accumulated by pass3 atomics
// dftp  : f32  [b][8][64][64]
static const size_t OFF_XH    = 0;
static const size_t OFF_XT    = 16777216;
static const size_t OFF_TABB  = 33554432;
static const size_t OFF_TABT  = 33685504;
static const size_t OFF_MAH   = 33816576;   // 262,144 slots
static const size_t OFF_PWWH  = 34078720;   // 8,192
static const size_t OFF_W1H   = 34086912;   // 4,096
static const size_t OFF_COND  = 34091008;   // 8,192
static const size_t OFF_STATS = 34099200;   // 16,384
static const size_t OFF_DFTP  = 34115584;   // 4,194,304
// end = 38,309,888 slots = 153 MB (< proven 157.4 MB footprint)

// ---------------- trig tables + weight fp16 conversion ----------------
__global__ void k_tab(unsigned short* __restrict__ tabB, unsigned short* __restrict__ tabT,
                      const float* __restrict__ pww, unsigned short* __restrict__ pwwh,
                      const float* __restrict__ pj1w, unsigned short* __restrict__ w1h){
    int t = blockIdx.x*256 + threadIdx.x;        // 262144
    if (t < 16384) pwwh[t] = f2h(pww[t]);
    if (t < 8192)  w1h[t]  = f2h(pj1w[t]);
    int m2 = t >> 12, n = t & 4095;
    int m = m2 & 31;
    int r = (m*n) & 4095;
    double a = (double)r * (6.283185307179586476925286766559 / 4096.0);
    float v = (m2 >= 32) ? (float)sin(a) : (float)cos(a);
    tabB[(size_t)m2*4096 + n] = f2h(v);
    tabT[(size_t)n*64 + m2]   = f2h(v * 0.015625f);
}

// ---------------- conditioning MLP ----------------
__global__ __launch_bounds__(64) void k_cond(const float* __restrict__ instp,
        const float* __restrict__ w1, const float* __restrict__ b1,
        const float* __restrict__ w2, const float* __restrict__ b2,
        float* __restrict__ cond){
    int b = blockIdx.x, tid = threadIdx.x;
    __shared__ float ipl[8];
    __shared__ float tl[64];
    if (tid < 8) ipl[tid] = instp[b*8 + tid];
    __syncthreads();
    float s = b1[tid];
    #pragma unroll
    for (int k = 0; k < 8; ++k) s = fmaf(ipl[k], w1[k*64 + tid], s);
    tl[tid] = gelu_f(s);
    __syncthreads();
    float c = b2[tid];
    #pragma unroll 8
    for (int j = 0; j < 64; ++j) c = fmaf(tl[j], w2[j*64 + tid], c);
    cond[b*64 + tid] = c;
}

// ---------------- lift + interp + cond -> xh (fp16) ----------------
// grid (64 wc, 8 bg), 256 thr. lift_w column-block staged ONCE per block.
__global__ __launch_bounds__(256) void k_lift(const float* __restrict__ z,
        const float* __restrict__ lw, const float* __restrict__ lb,
        const float* __restrict__ cond, unsigned short* __restrict__ xh){
    int wc = blockIdx.x;
    int b0 = blockIdx.y * 16;
    int t = threadIdx.x;
    __shared__ float lwl[128*64];   // [d][pos]
    __shared__ float zl[16*128];    // [bb][d]
    __shared__ float x0[16*64];     // [bb][pos]
    #pragma unroll
    for (int i = 0; i < 32; ++i){
        int idx = i*256 + t;
        lwl[idx] = lw[(size_t)(idx >> 6)*4096 + wc*64 + (idx & 63)];
    }
    #pragma unroll
    for (int i = 0; i < 8; ++i){
        int idx = i*256 + t;
        zl[idx] = z[(b0 + (idx >> 7))*128 + (idx & 127)];
    }
    __syncthreads();
    #pragma unroll
    for (int i = 0; i < 4; ++i){
        int idx = i*256 + t;
        int bb = idx >> 6, pos = idx & 63;
        float s = 0.f;
        #pragma unroll 8
        for (int d = 0; d < 128; ++d)
            s = fmaf(zl[bb*128 + d], lwl[d*64 + pos], s);
        // cond is per-CHANNEL (wc), broadcast over positions
        x0[idx] = s + lb[wc*64 + pos] + cond[(b0 + bb)*64 + wc];
    }
    __syncthreads();
    for (int bb = 0; bb < 16; ++bb){
        const float* xr = x0 + bb*64;
        unsigned int pk[8];
        #pragma unroll
        for (int i = 0; i < 8; ++i){
            float v[2];
            #pragma unroll
            for (int q = 0; q < 2; ++q){
                int n = t*16 + i*2 + q;
                float src = (n + 0.5f)*0.015625f - 0.5f;
                src = fminf(fmaxf(src, 0.0f), 63.0f);
                int i0 = (int)src;
                int i1 = (i0 + 1 > 63) ? 63 : (i0 + 1);
                float wt = src - (float)i0;
                v[q] = xr[i0] + wt*(xr[i1] - xr[i0]);
            }
            pk[i] = (unsigned int)f2h(v[0]) | ((unsigned int)f2h(v[1]) << 16);
        }
        unsigned short* dst = xh + ((size_t)((b0 + bb)*64 + wc))*4096 + t*16;
        *(uint4*)dst       = make_uint4(pk[0],pk[1],pk[2],pk[3]);
        *(uint4*)(dst + 8) = make_uint4(pk[4],pk[5],pk[6],pk[7]);
    }
}

// ---------------- prep: norm+gelu -> x, transpose-store xT, forward-DFT ----------------
// double-buffered LDS tile: ONE barrier per iter.
template<int NORM, int DODFT>
__global__ __launch_bounds__(256) void k_prep(
        const unsigned short* __restrict__ xhp, const float* __restrict__ statsr,
        const unsigned short* __restrict__ tabB, unsigned short* __restrict__ xT,
        float* __restrict__ dftp)
{
    int b = blockIdx.x, ng = blockIdx.y;
    int t = threadIdx.x;
    int w = t >> 6, lane = t & 63;
    int lrow = lane & 15, g = lane >> 4;
    __shared__ __align__(16) unsigned short xl[2][4096];
    int co = t >> 2, nq = t & 3;
    float mu = 0.f, rs = 1.f;
    if (NORM){
        float2 sr = *(const float2*)(statsr + (size_t)(b*64+co)*2);
        mu = sr.x * (1.f/4096.f);
        float var = fmaf(sr.y, 1.f/4096.f, -mu*mu);
        rs = rsqrtf(var + 1e-5f);
    }
    fx4 acc[4];
    #pragma unroll
    for (int i = 0; i < 4; ++i) acc[i] = (fx4){0.f,0.f,0.f,0.f};

    const unsigned short* hrow = xhp + ((size_t)(b*64+co))*4096 + ng*512 + nq*16;
    unsigned short* xtbase = xT + ((size_t)b*4096 + (size_t)ng*512)*64;

    for (int it = 0; it < 8; ++it){
        int n0 = ng*512 + it*64;
        char* xb = (char*)(&xl[it & 1][0]);
        uint4 hA = *(const uint4*)(hrow + it*64);
        uint4 hB = *(const uint4*)(hrow + it*64 + 8);
        unsigned int pk[8];
        if (NORM){
            unsigned int hu[8] = {hA.x,hA.y,hA.z,hA.w,hB.x,hB.y,hB.z,hB.w};
            #pragma unroll
            for (int i = 0; i < 8; ++i){
                float f0 = h2f((unsigned short)(hu[i] & 0xFFFFu));
                float f1 = h2f((unsigned short)(hu[i] >> 16));
                f0 = gelu_f((f0 - mu)*rs);
                f1 = gelu_f((f1 - mu)*rs);
                pk[i] = (unsigned int)f2h(f0) | ((unsigned int)f2h(f1) << 16);
            }
        } else {
            pk[0]=hA.x; pk[1]=hA.y; pk[2]=hA.z; pk[3]=hA.w;
            pk[4]=hB.x; pk[5]=hB.y; pk[6]=hB.z; pk[7]=hB.w;
        }
        unsigned int base = (unsigned int)co*128 + (unsigned int)nq*32;
        unsigned int sw = (unsigned int)((co & 7) << 4);
        *(uint4*)(xb + ((base +  0) ^ sw)) = make_uint4(pk[0],pk[1],pk[2],pk[3]);
        *(uint4*)(xb + ((base + 16) ^ sw)) = make_uint4(pk[4],pk[5],pk[6],pk[7]);
        __syncthreads();

        if (DODFT){
            int m0 = w*16;
            #pragma unroll
            for (int ks = 0; ks < 2; ++ks){
                int kk = ks*32 + g*8;
                half8 af = *(const half8*)(tabB + (size_t)(m0 + lrow)*4096 + n0 + kk);
                #pragma unroll
                for (int ct = 0; ct < 4; ++ct){
                    int row = ct*16 + lrow;
                    unsigned int ba = ((unsigned int)row*128 + (unsigned int)kk*2)
                                      ^ (unsigned int)((row & 7) << 4);
                    half8 bf = *(const half8*)(xb + ba);
                    acc[ct] = __builtin_amdgcn_mfma_f32_16x16x32_f16(af, bf, acc[ct], 0, 0, 0);
                }
            }
        }
        {   // transpose out: xT[b][n][co]
            int n = t & 63, coq = t >> 6;
            unsigned int opk[8];
            #pragma unroll
            for (int i = 0; i < 8; ++i){
                int r0 = coq*16 + 2*i, r1 = r0 + 1;
                unsigned int a0 = ((unsigned int)r0*128 + (unsigned int)n*2)
                                  ^ (unsigned int)((r0 & 7) << 4);
                unsigned int a1 = ((unsigned int)r1*128 + (unsigned int)n*2)
                                  ^ (unsigned int)((r1 & 7) << 4);
                unsigned short v0 = *(const unsigned short*)(xb + a0);
                unsigned short v1 = *(const unsigned short*)(xb + a1);
                opk[i] = (unsigned int)v0 | ((unsigned int)v1 << 16);
            }
            unsigned short* dst = xtbase + (size_t)(it*64 + n)*64 + coq*16;
            *(uint4*)dst       = make_uint4(opk[0],opk[1],opk[2],opk[3]);
            *(uint4*)(dst + 8) = make_uint4(opk[4],opk[5],opk[6],opk[7]);
        }
        // no second barrier: next iter writes the other buffer; the compiler's
        // waitcnt-before-s_barrier drains this iter's LDS reads at the next sync
    }
    if (DODFT){
        int m0 = w*16;
        #pragma unroll
        for (int ct = 0; ct < 4; ++ct){
            #pragma unroll
            for (int j = 0; j < 4; ++j){
                dftp[((size_t)(b*8+ng)*64 + m0 + g*4 + j)*64 + ct*16 + lrow] = acc[ct][j];
            }
        }
    }
}

// ---------------- spectral mix (fused dftred + stats zero) ----------------
// grid (128 b), 256 thr.
__global__ __launch_bounds__(256) void k_mix(const float* __restrict__ dftp,
        const float* __restrict__ specw, unsigned short* __restrict__ mah,
        float* __restrict__ statsr, int l){
    int b = blockIdx.x, t = threadIdx.x;
    __shared__ float xm[4096];               // [32 m][64 ci][2]
    if (t < 128) statsr[b*128 + t] = 0.f;    // zero raw stats for this layer's pass3
    const float* dp = dftp + (size_t)b*8*4096;
    #pragma unroll
    for (int i = 0; i < 16; ++i){
        int e = i*256 + t;                   // e = m2*64 + ci
        float s = 0.f;
        #pragma unroll
        for (int ng = 0; ng < 8; ++ng) s += dp[ng*4096 + e];
        int m2 = e >> 6, ci = e & 63;
        if (m2 < 32) xm[(m2*64 + ci)*2] = s;           // Xr
        else         xm[((m2-32)*64 + ci)*2 + 1] = -s; // Xi = -sum(sin)
    }
    __syncthreads();
    int co = t >> 2, mq = t & 3;
    float yr[8] = {0,0,0,0,0,0,0,0}, yi[8] = {0,0,0,0,0,0,0,0};
    const float* wbase = specw + (size_t)(l*64)*4096 + co*64 + mq*16;
    for (int ci = 0; ci < 64; ++ci){
        const float* wp = wbase + (size_t)ci*4096;
        float4 w0 = *(const float4*)(wp);
        float4 w1v = *(const float4*)(wp + 4);
        float4 w2v = *(const float4*)(wp + 8);
        float4 w3v = *(const float4*)(wp + 12);
        float wr[8] = {w0.x,w0.z,w1v.x,w1v.z,w2v.x,w2v.z,w3v.x,w3v.z};
        float wi[8] = {w0.y,w0.w,w1v.y,w1v.w,w2v.y,w2v.w,w3v.y,w3v.w};
        #pragma unroll
        for (int mm = 0; mm < 8; ++mm){
            int m = mq*8 + mm;
            float2 x = *(const float2*)(xm + (m*64 + ci)*2);
            yr[mm] = fmaf(x.x, wr[mm], fmaf(-x.y, wi[mm], yr[mm]));
            yi[mm] = fmaf(x.x, wi[mm], fmaf( x.y, wr[mm], yi[mm]));
        }
    }
    unsigned short* mb = mah + (size_t)(b*64 + co)*64;
    #pragma unroll
    for (int mm = 0; mm < 8; ++mm){
        int m = mq*8 + mm;
        float sc = (m == 0) ? 0.015625f : 0.03125f;   // (1|2)/4096 * 64
        mb[m]      = f2h(sc * yr[mm]);
        mb[32 + m] = f2h(-0.03125f * yi[mm]);
    }
}

// ---------------- fused pointwise + iDFT (MFMA) -> h fp16 + raw-stat atomics ----------------
__global__ __launch_bounds__(256) void k_pass3(
        const unsigned short* __restrict__ xT, const unsigned short* __restrict__ tabT,
        const unsigned short* __restrict__ pwwh, const float* __restrict__ pwb,
        const unsigned short* __restrict__ mah, unsigned short* __restrict__ xh,
        float* __restrict__ statsr, int lay)
{
    int b = blockIdx.x, ntg = blockIdx.y;
    int n0 = ntg*256;
    int t = threadIdx.x, w = t >> 6, lane = t & 63;
    int lrow = lane & 15, g = lane >> 4;

    half8 A[4][4];
    #pragma unroll
    for (int ct = 0; ct < 4; ++ct){
        int co = ct*16 + lrow;
        #pragma unroll
        for (int ks = 0; ks < 4; ++ks){
            int k = ks*32 + g*8;
            const unsigned short* src = (k < 64)
                ? (pwwh + ((size_t)lay*64 + co)*64 + k)
                : (mah  + ((size_t)b*64 + co)*64 + (k - 64));
            A[ct][ks] = *(const half8*)src;
        }
    }
    fx4 acc[4][4];
    #pragma unroll
    for (int i = 0; i < 4; ++i)
        #pragma unroll
        for (int j = 0; j < 4; ++j) acc[i][j] = (fx4){0.f,0.f,0.f,0.f};

    #pragma unroll
    for (int ks = 0; ks < 4; ++ks){
        int k = ks*32 + g*8;
        #pragma unroll
        for (int ntl = 0; ntl < 4; ++ntl){
            int n = n0 + (w*4 + ntl)*16 + lrow;
            const unsigned short* bs = (k < 64) ? (xT + ((size_t)b*4096 + n)*64 + k)
                                                : (tabT + (size_t)n*64 + (k - 64));
            half8 bf = *(const half8*)bs;
            #pragma unroll
            for (int ct = 0; ct < 4; ++ct)
                acc[ct][ntl] = __builtin_amdgcn_mfma_f32_16x16x32_f16(A[ct][ks], bf, acc[ct][ntl], 0, 0, 0);
        }
    }
    __shared__ float sred[2][4][64];
    #pragma unroll
    for (int ct = 0; ct < 4; ++ct){
        #pragma unroll
        for (int j = 0; j < 4; ++j){
            int co = ct*16 + g*4 + j;
            float pb = pwb[lay*64 + co];
            unsigned short* hr = xh + ((size_t)(b*64+co))*4096;
            float s = 0.f, q = 0.f;
            #pragma unroll
            for (int ntl = 0; ntl < 4; ++ntl){
                int n = n0 + (w*4+ntl)*16 + lrow;
                float h = acc[ct][ntl][j] + pb;
                hr[n] = f2h(h);
                s += h; q = fmaf(h, h, q);
            }
            #pragma unroll
            for (int e = 1; e < 16; e <<= 1){ s += __shfl_xor(s, e); q += __shfl_xor(q, e); }
            if (lrow == 0){
                sred[0][w][co] = s;
                sred[1][w][co] = q;
            }
        }
    }
    __syncthreads();
    if (t < 64){
        float S = 0.f, Q = 0.f;
        #pragma unroll
        for (int ww = 0; ww < 4; ++ww){ S += sred[0][ww][t]; Q += sred[1][ww][t]; }
        atomicAdd(statsr + (size_t)(b*64+t)*2,     S);
        atomicAdd(statsr + (size_t)(b*64+t)*2 + 1, Q);
    }
}

// ---------------- projection head (8 waves, 8 tiles per wave) ----------------
// grid (128 b, 8 ntg of 512 n), 512 thr. A/bias/w2 loaded once per 128 cols.
__global__ __launch_bounds__(512) void k_proj(
        const unsigned short* __restrict__ xT, const unsigned short* __restrict__ w1h,
        const float* __restrict__ b1, const float* __restrict__ w2,
        const float* __restrict__ b2, float* __restrict__ out)
{
    int b = blockIdx.x, ntg = blockIdx.y;
    int t = threadIdx.x, w = t >> 6, lane = t & 63;
    int lrow = lane & 15, g = lane >> 4;
    int o2h = w & 1, nq = w >> 1;
    int nb = ntg*512 + nq*128;

    half8 A[4][2];
    #pragma unroll
    for (int ot = 0; ot < 4; ++ot)
        #pragma unroll
        for (int ks = 0; ks < 2; ++ks)
            A[ot][ks] = *(const half8*)(w1h + (size_t)(o2h*64 + ot*16 + lrow)*64 + ks*32 + g*8);
    float bb[16], wv[16];
    #pragma unroll
    for (int ot = 0; ot < 4; ++ot)
        #pragma unroll
        for (int j = 0; j < 4; ++j){
            int o2 = o2h*64 + ot*16 + g*4 + j;
            bb[ot*4+j] = b1[o2];
            wv[ot*4+j] = w2[o2];
        }
    __shared__ float sred[4][8][2][16];
    for (int tl = 0; tl < 8; ++tl){
        int n = nb + tl*16 + lrow;
        fx4 acc[4];
        #pragma unroll
        for (int i = 0; i < 4; ++i) acc[i] = (fx4){0.f,0.f,0.f,0.f};
        #pragma unroll
        for (int ks = 0; ks < 2; ++ks){
            half8 bf = *(const half8*)(xT + ((size_t)b*4096 + n)*64 + ks*32 + g*8);
            #pragma unroll
            for (int ot = 0; ot < 4; ++ot)
                acc[ot] = __builtin_amdgcn_mfma_f32_16x16x32_f16(A[ot][ks], bf, acc[ot], 0, 0, 0);
        }
        float p = 0.f;
        #pragma unroll
        for (int ot = 0; ot < 4; ++ot)
            #pragma unroll
            for (int j = 0; j < 4; ++j)
                p = fmaf(wv[ot*4+j], gelu_f(acc[ot][j] + bb[ot*4+j]), p);
        p += __shfl_xor(p, 16); p += __shfl_xor(p, 32);
        if (lane < 16) sred[nq][tl][o2h][lane] = p;
    }
    __syncthreads();
    {
        int cl = t & 15, tlf = (t >> 4) & 7, nqf = t >> 7;
        out[(size_t)b*4096 + ntg*512 + t] =
            sred[nqf][tlf][0][cl] + sred[nqf][tlf][1][cl] + b2[0];
    }
}

// ---------------- launch ----------------
extern "C" void kernel_launch(void* const* d_in, const int* in_sizes, int n_in,
                              void* d_out, int out_size, void* d_ws, size_t ws_size,
                              hipStream_t stream) {
    (void)in_sizes; (void)n_in; (void)out_size; (void)ws_size;
    const float* z      = (const float*)d_in[0];
    const float* instp  = (const float*)d_in[1];
    const float* lift_w = (const float*)d_in[2];
    const float* lift_b = (const float*)d_in[3];
    const float* iw1    = (const float*)d_in[4];
    const float* ib1    = (const float*)d_in[5];
    const float* iw2    = (const float*)d_in[6];
    const float* ib2    = (const float*)d_in[7];
    const float* specw  = (const float*)d_in[8];
    const float* pww    = (const float*)d_in[9];
    const float* pwb    = (const float*)d_in[10];
    const float* pj1w   = (const float*)d_in[11];
    const float* pj1b   = (const float*)d_in[12];
    const float* pj2w   = (const float*)d_in[13];
    const float* pj2b   = (const float*)d_in[14];

    float* ws = (float*)d_ws;
    unsigned short* xh    = (unsigned short*)(ws + OFF_XH);
    unsigned short* xT    = (unsigned short*)(ws + OFF_XT);
    unsigned short* tabB  = (unsigned short*)(ws + OFF_TABB);
    unsigned short* tabT  = (unsigned short*)(ws + OFF_TABT);
    unsigned short* mah   = (unsigned short*)(ws + OFF_MAH);
    unsigned short* pwwh  = (unsigned short*)(ws + OFF_PWWH);
    unsigned short* w1h   = (unsigned short*)(ws + OFF_W1H);
    float* cond   = ws + OFF_COND;
    float* statsr = ws + OFF_STATS;
    float* dftp   = ws + OFF_DFTP;
    float* out    = (float*)d_out;

    k_tab <<<dim3(1024),  dim3(256), 0, stream>>>(tabB, tabT, pww, pwwh, pj1w, w1h);
    k_cond<<<dim3(128),   dim3(64),  0, stream>>>(instp, iw1, ib1, iw2, ib2, cond);
    k_lift<<<dim3(64, 8), dim3(256), 0, stream>>>(z, lift_w, lift_b, cond, xh);

    for (int l = 0; l < 4; ++l){
        if (l == 0)
            k_prep<0,1><<<dim3(128,8), dim3(256), 0, stream>>>(xh, statsr, tabB, xT, dftp);
        else
            k_prep<1,1><<<dim3(128,8), dim3(256), 0, stream>>>(xh, statsr, tabB, xT, dftp);
        k_mix  <<<dim3(128),    dim3(256), 0, stream>>>(dftp, specw, mah, statsr, l);
        k_pass3<<<dim3(128,16), dim3(256), 0, stream>>>(xT, tabT, pwwh, pwb, mah, xh, statsr, l);
    }
    k_prep<1,0><<<dim3(128,8), dim3(256), 0, stream>>>(xh, statsr, tabB, xT, dftp);
    k_proj    <<<dim3(128,8),  dim3(512), 0, stream>>>(xT, w1h, pj1b, pj2w, pj2b, out);
}

// Round 7
// 603.895 us; speedup vs baseline: 2.8008x; 1.0029x over previous
//
#include <hip/hip_runtime.h>
#include <math.h>

// B=128, W=64, L=4096, MODES=32, N_LAYERS=4

typedef _Float16 half8 __attribute__((ext_vector_type(8)));  // 8 fp16 (4 VGPR)
typedef __attribute__((ext_vector_type(4))) float fx4;       // MFMA f32 acc

// fast gelu: tanh/sigmoid form, exp2-folded. gelu(x) ~= x * sigmoid(2y),
// 2y*log2e = x*(2.3022083 + 0.1029443*x^2). Max dev from exact-erf ~5e-4.
__device__ __forceinline__ float gelu_f(float x){
    float u = x*x;
    float a = x * fmaf(-0.1029443f, u, -2.3022083f);   // -2y*log2(e)
    float e = exp2f(a);                                 // e^{-2y}
    float r = __builtin_amdgcn_rcpf(1.0f + e);          // sigmoid(2y)
    return x * r;
}
__device__ __forceinline__ unsigned short f2h(float f){
    union { _Float16 h; unsigned short u; } c;
    c.h = (_Float16)f;
    return c.u;
}
__device__ __forceinline__ float h2f(unsigned short u){
    union { unsigned short u; _Float16 h; } c;
    c.u = u;
    return (float)c.h;
}

// ---------------- workspace layout (float-slot offsets) ----------------
// xh    : fp16 [128][64][4096]  h / x0 (channel-major)
// xT    : fp16 [128][4096][64]  normalized x, position-major
// tabB  : fp16 [64][4096]       rows 0-31 cos, 32-63 sin (fwd DFT)
// tabT  : fp16 [4096][64]       transpose, scaled 1/64 (iDFT)
// mah   : fp16 [b][co][64]      iDFT coeffs x64
// pwwh  : fp16 [4][64][64]
// w1h   : fp16 [128][64]
// cond  : f32  [b][64]
// statsr: f32  [b][co][2]       RAW (S, Q) accumulated by pass3 atomics
// dftp  : f32  [b][8][64][64]
static const size_t OFF_XH    = 0;
static const size_t OFF_XT    = 16777216;
static const size_t OFF_TABB  = 33554432;
static const size_t OFF_TABT  = 33685504;
static const size_t OFF_MAH   = 33816576;   // 262,144 slots
static const size_t OFF_PWWH  = 34078720;   // 8,192
static const size_t OFF_W1H   = 34086912;   // 4,096
static const size_t OFF_COND  = 34091008;   // 8,192
static const size_t OFF_STATS = 34099200;   // 16,384
static const size_t OFF_DFTP  = 34115584;   // 4,194,304
// end = 38,309,888 slots = 153 MB (< proven 157.4 MB footprint)

// ---------------- trig tables + weight fp16 conversion ----------------
__global__ void k_tab(unsigned short* __restrict__ tabB, unsigned short* __restrict__ tabT,
                      const float* __restrict__ pww, unsigned short* __restrict__ pwwh,
                      const float* __restrict__ pj1w, unsigned short* __restrict__ w1h){
    int t = blockIdx.x*256 + threadIdx.x;        // 262144
    if (t < 16384) pwwh[t] = f2h(pww[t]);
    if (t < 8192)  w1h[t]  = f2h(pj1w[t]);
    int m2 = t >> 12, n = t & 4095;
    int m = m2 & 31;
    int r = (m*n) & 4095;
    int r2 = (r >= 2048) ? (r - 4096) : r;       // fold to [-pi, pi)
    float a = (float)r2 * 1.5339807878856412e-3f;   // 2*pi/4096
    float v = (m2 >= 32) ? sinf(a) : cosf(a);
    tabB[(size_t)m2*4096 + n] = f2h(v);
    tabT[(size_t)n*64 + m2]   = f2h(v * 0.015625f);
}

// ---------------- conditioning MLP ----------------
__global__ __launch_bounds__(64) void k_cond(const float* __restrict__ instp,
        const float* __restrict__ w1, const float* __restrict__ b1,
        const float* __restrict__ w2, const float* __restrict__ b2,
        float* __restrict__ cond){
    int b = blockIdx.x, tid = threadIdx.x;
    __shared__ float ipl[8];
    __shared__ float tl[64];
    if (tid < 8) ipl[tid] = instp[b*8 + tid];
    __syncthreads();
    float s = b1[tid];
    #pragma unroll
    for (int k = 0; k < 8; ++k) s = fmaf(ipl[k], w1[k*64 + tid], s);
    tl[tid] = gelu_f(s);
    __syncthreads();
    float c = b2[tid];
    #pragma unroll 8
    for (int j = 0; j < 64; ++j) c = fmaf(tl[j], w2[j*64 + tid], c);
    cond[b*64 + tid] = c;
}

// ---------------- lift + interp + cond -> xh (fp16) ----------------
// grid (64 wc, 8 bg), 256 thr. lift_w column-block staged ONCE per block.
__global__ __launch_bounds__(256) void k_lift(const float* __restrict__ z,
        const float* __restrict__ lw, const float* __restrict__ lb,
        const float* __restrict__ cond, unsigned short* __restrict__ xh){
    int wc = blockIdx.x;
    int b0 = blockIdx.y * 16;
    int t = threadIdx.x;
    __shared__ float lwl[128*64];   // [d][pos]
    __shared__ float zl[16*128];    // [bb][d]
    __shared__ float x0[16*64];     // [bb][pos]
    #pragma unroll
    for (int i = 0; i < 32; ++i){
        int idx = i*256 + t;
        lwl[idx] = lw[(size_t)(idx >> 6)*4096 + wc*64 + (idx & 63)];
    }
    #pragma unroll
    for (int i = 0; i < 8; ++i){
        int idx = i*256 + t;
        zl[idx] = z[(b0 + (idx >> 7))*128 + (idx & 127)];
    }
    __syncthreads();
    #pragma unroll
    for (int i = 0; i < 4; ++i){
        int idx = i*256 + t;
        int bb = idx >> 6, pos = idx & 63;
        float s = 0.f;
        #pragma unroll 8
        for (int d = 0; d < 128; ++d)
            s = fmaf(zl[bb*128 + d], lwl[d*64 + pos], s);
        // cond is per-CHANNEL (wc), broadcast over positions
        x0[idx] = s + lb[wc*64 + pos] + cond[(b0 + bb)*64 + wc];
    }
    __syncthreads();
    for (int bb = 0; bb < 16; ++bb){
        const float* xr = x0 + bb*64;
        unsigned int pk[8];
        #pragma unroll
        for (int i = 0; i < 8; ++i){
            float v[2];
            #pragma unroll
            for (int q = 0; q < 2; ++q){
                int n = t*16 + i*2 + q;
                float src = (n + 0.5f)*0.015625f - 0.5f;
                src = fminf(fmaxf(src, 0.0f), 63.0f);
                int i0 = (int)src;
                int i1 = (i0 + 1 > 63) ? 63 : (i0 + 1);
                float wt = src - (float)i0;
                v[q] = xr[i0] + wt*(xr[i1] - xr[i0]);
            }
            pk[i] = (unsigned int)f2h(v[0]) | ((unsigned int)f2h(v[1]) << 16);
        }
        unsigned short* dst = xh + ((size_t)((b0 + bb)*64 + wc))*4096 + t*16;
        *(uint4*)dst       = make_uint4(pk[0],pk[1],pk[2],pk[3]);
        *(uint4*)(dst + 8) = make_uint4(pk[4],pk[5],pk[6],pk[7]);
    }
}

// ---------------- prep: norm+gelu -> x, transpose-store xT, forward-DFT ----------------
// double-buffered LDS tile, ONE barrier per iter, global loads prefetched 1 iter ahead.
template<int NORM, int DODFT>
__global__ __launch_bounds__(256) void k_prep(
        const unsigned short* __restrict__ xhp, const float* __restrict__ statsr,
        const unsigned short* __restrict__ tabB, unsigned short* __restrict__ xT,
        float* __restrict__ dftp)
{
    int b = blockIdx.x, ng = blockIdx.y;
    int t = threadIdx.x;
    int w = t >> 6, lane = t & 63;
    int lrow = lane & 15, g = lane >> 4;
    __shared__ __align__(16) unsigned short xl[2][4096];
    int co = t >> 2, nq = t & 3;
    float mu = 0.f, rs = 1.f;
    if (NORM){
        float2 sr = *(const float2*)(statsr + (size_t)(b*64+co)*2);
        mu = sr.x * (1.f/4096.f);
        float var = fmaf(sr.y, 1.f/4096.f, -mu*mu);
        rs = rsqrtf(var + 1e-5f);
    }
    fx4 acc[4];
    #pragma unroll
    for (int i = 0; i < 4; ++i) acc[i] = (fx4){0.f,0.f,0.f,0.f};

    const unsigned short* hrow = xhp + ((size_t)(b*64+co))*4096 + ng*512 + nq*16;
    unsigned short* xtbase = xT + ((size_t)b*4096 + (size_t)ng*512)*64;

    uint4 cA = *(const uint4*)(hrow);
    uint4 cB = *(const uint4*)(hrow + 8);
    for (int it = 0; it < 8; ++it){
        int n0 = ng*512 + it*64;
        char* xb = (char*)(&xl[it & 1][0]);
        uint4 nA, nB;
        if (it < 7){                                  // prefetch next iter's tile
            nA = *(const uint4*)(hrow + (it+1)*64);
            nB = *(const uint4*)(hrow + (it+1)*64 + 8);
        }
        unsigned int pk[8];
        if (NORM){
            unsigned int hu[8] = {cA.x,cA.y,cA.z,cA.w,cB.x,cB.y,cB.z,cB.w};
            #pragma unroll
            for (int i = 0; i < 8; ++i){
                float f0 = h2f((unsigned short)(hu[i] & 0xFFFFu));
                float f1 = h2f((unsigned short)(hu[i] >> 16));
                f0 = gelu_f((f0 - mu)*rs);
                f1 = gelu_f((f1 - mu)*rs);
                pk[i] = (unsigned int)f2h(f0) | ((unsigned int)f2h(f1) << 16);
            }
        } else {
            pk[0]=cA.x; pk[1]=cA.y; pk[2]=cA.z; pk[3]=cA.w;
            pk[4]=cB.x; pk[5]=cB.y; pk[6]=cB.z; pk[7]=cB.w;
        }
        unsigned int base = (unsigned int)co*128 + (unsigned int)nq*32;
        unsigned int sw = (unsigned int)((co & 7) << 4);
        *(uint4*)(xb + ((base +  0) ^ sw)) = make_uint4(pk[0],pk[1],pk[2],pk[3]);
        *(uint4*)(xb + ((base + 16) ^ sw)) = make_uint4(pk[4],pk[5],pk[6],pk[7]);
        __syncthreads();

        if (DODFT){
            int m0 = w*16;
            #pragma unroll
            for (int ks = 0; ks < 2; ++ks){
                int kk = ks*32 + g*8;
                half8 af = *(const half8*)(tabB + (size_t)(m0 + lrow)*4096 + n0 + kk);
                #pragma unroll
                for (int ct = 0; ct < 4; ++ct){
                    int row = ct*16 + lrow;
                    unsigned int ba = ((unsigned int)row*128 + (unsigned int)kk*2)
                                      ^ (unsigned int)((row & 7) << 4);
                    half8 bf = *(const half8*)(xb + ba);
                    acc[ct] = __builtin_amdgcn_mfma_f32_16x16x32_f16(af, bf, acc[ct], 0, 0, 0);
                }
            }
        }
        {   // transpose out: xT[b][n][co]
            int n = t & 63, coq = t >> 6;
            unsigned int opk[8];
            #pragma unroll
            for (int i = 0; i < 8; ++i){
                int r0 = coq*16 + 2*i, r1 = r0 + 1;
                unsigned int a0 = ((unsigned int)r0*128 + (unsigned int)n*2)
                                  ^ (unsigned int)((r0 & 7) << 4);
                unsigned int a1 = ((unsigned int)r1*128 + (unsigned int)n*2)
                                  ^ (unsigned int)((r1 & 7) << 4);
                unsigned short v0 = *(const unsigned short*)(xb + a0);
                unsigned short v1 = *(const unsigned short*)(xb + a1);
                opk[i] = (unsigned int)v0 | ((unsigned int)v1 << 16);
            }
            unsigned short* dst = xtbase + (size_t)(it*64 + n)*64 + coq*16;
            *(uint4*)dst       = make_uint4(opk[0],opk[1],opk[2],opk[3]);
            *(uint4*)(dst + 8) = make_uint4(opk[4],opk[5],opk[6],opk[7]);
        }
        if (it < 7){ cA = nA; cB = nB; }
        // no second barrier: next iter writes the other LDS buffer; the
        // waitcnt before the next s_barrier drains this iter's LDS reads
    }
    if (DODFT){
        int m0 = w*16;
        #pragma unroll
        for (int ct = 0; ct < 4; ++ct){
            #pragma unroll
            for (int j = 0; j < 4; ++j){
                dftp[((size_t)(b*8+ng)*64 + m0 + g*4 + j)*64 + ct*16 + lrow] = acc[ct][j];
            }
        }
    }
}

// ---------------- spectral mix (fused dftred + stats zero) ----------------
// grid (128 b), 256 thr.
__global__ __launch_bounds__(256) void k_mix(const float* __restrict__ dftp,
        const float* __restrict__ specw, unsigned short* __restrict__ mah,
        float* __restrict__ statsr, int l){
    int b = blockIdx.x, t = threadIdx.x;
    __shared__ float xm[4096];               // [32 m][64 ci][2]
    if (t < 128) statsr[b*128 + t] = 0.f;    // zero raw stats for this layer's pass3
    const float* dp = dftp + (size_t)b*8*4096;
    #pragma unroll
    for (int i = 0; i < 16; ++i){
        int e = i*256 + t;                   // e = m2*64 + ci
        float s = 0.f;
        #pragma unroll
        for (int ng = 0; ng < 8; ++ng) s += dp[ng*4096 + e];
        int m2 = e >> 6, ci = e & 63;
        if (m2 < 32) xm[(m2*64 + ci)*2] = s;           // Xr
        else         xm[((m2-32)*64 + ci)*2 + 1] = -s; // Xi = -sum(sin)
    }
    __syncthreads();
    int co = t >> 2, mq = t & 3;
    float yr[8] = {0,0,0,0,0,0,0,0}, yi[8] = {0,0,0,0,0,0,0,0};
    const float* wbase = specw + (size_t)(l*64)*4096 + co*64 + mq*16;
    for (int ci = 0; ci < 64; ++ci){
        const float* wp = wbase + (size_t)ci*4096;
        float4 w0 = *(const float4*)(wp);
        float4 w1v = *(const float4*)(wp + 4);
        float4 w2v = *(const float4*)(wp + 8);
        float4 w3v = *(const float4*)(wp + 12);
        float wr[8] = {w0.x,w0.z,w1v.x,w1v.z,w2v.x,w2v.z,w3v.x,w3v.z};
        float wi[8] = {w0.y,w0.w,w1v.y,w1v.w,w2v.y,w2v.w,w3v.y,w3v.w};
        #pragma unroll
        for (int mm = 0; mm < 8; ++mm){
            int m = mq*8 + mm;
            float2 x = *(const float2*)(xm + (m*64 + ci)*2);
            yr[mm] = fmaf(x.x, wr[mm], fmaf(-x.y, wi[mm], yr[mm]));
            yi[mm] = fmaf(x.x, wi[mm], fmaf( x.y, wr[mm], yi[mm]));
        }
    }
    unsigned short* mb = mah + (size_t)(b*64 + co)*64;
    #pragma unroll
    for (int mm = 0; mm < 8; ++mm){
        int m = mq*8 + mm;
        float sc = (m == 0) ? 0.015625f : 0.03125f;   // (1|2)/4096 * 64
        mb[m]      = f2h(sc * yr[mm]);
        mb[32 + m] = f2h(-0.03125f * yi[mm]);
    }
}

// ---------------- fused pointwise + iDFT (MFMA) -> h fp16 + raw-stat atomics ----------------
// Register-rich: all 16 A-frags + 16 B-frags loaded up front (32 outstanding
// 16B loads/thread), then 64 MFMAs. launch_bounds(256,2) allows ~256 VGPR.
__global__ __launch_bounds__(256, 2) void k_pass3(
        const unsigned short* __restrict__ xT, const unsigned short* __restrict__ tabT,
        const unsigned short* __restrict__ pwwh, const float* __restrict__ pwb,
        const unsigned short* __restrict__ mah, unsigned short* __restrict__ xh,
        float* __restrict__ statsr, int lay)
{
    int b = blockIdx.x, ntg = blockIdx.y;
    int n0 = ntg*256;
    int t = threadIdx.x, w = t >> 6, lane = t & 63;
    int lrow = lane & 15, g = lane >> 4;

    half8 A[4][4];
    #pragma unroll
    for (int ct = 0; ct < 4; ++ct){
        int co = ct*16 + lrow;
        #pragma unroll
        for (int ks = 0; ks < 4; ++ks){
            int k = ks*32 + g*8;
            const unsigned short* src = (k < 64)
                ? (pwwh + ((size_t)lay*64 + co)*64 + k)
                : (mah  + ((size_t)b*64 + co)*64 + (k - 64));
            A[ct][ks] = *(const half8*)src;
        }
    }
    half8 Bv[4][4];
    #pragma unroll
    for (int ks = 0; ks < 4; ++ks){
        int k = ks*32 + g*8;
        #pragma unroll
        for (int ntl = 0; ntl < 4; ++ntl){
            int n = n0 + (w*4 + ntl)*16 + lrow;
            const unsigned short* bs = (k < 64) ? (xT + ((size_t)b*4096 + n)*64 + k)
                                                : (tabT + (size_t)n*64 + (k - 64));
            Bv[ks][ntl] = *(const half8*)bs;
        }
    }
    fx4 acc[4][4];
    #pragma unroll
    for (int i = 0; i < 4; ++i)
        #pragma unroll
        for (int j = 0; j < 4; ++j) acc[i][j] = (fx4){0.f,0.f,0.f,0.f};

    #pragma unroll
    for (int ks = 0; ks < 4; ++ks)
        #pragma unroll
        for (int ntl = 0; ntl < 4; ++ntl)
            #pragma unroll
            for (int ct = 0; ct < 4; ++ct)
                acc[ct][ntl] = __builtin_amdgcn_mfma_f32_16x16x32_f16(A[ct][ks], Bv[ks][ntl], acc[ct][ntl], 0, 0, 0);

    __shared__ float sred[2][4][64];
    #pragma unroll
    for (int ct = 0; ct < 4; ++ct){
        #pragma unroll
        for (int j = 0; j < 4; ++j){
            int co = ct*16 + g*4 + j;
            float pb = pwb[lay*64 + co];
            unsigned short* hr = xh + ((size_t)(b*64+co))*4096;
            float s = 0.f, q = 0.f;
            #pragma unroll
            for (int ntl = 0; ntl < 4; ++ntl){
                int n = n0 + (w*4+ntl)*16 + lrow;
                float h = acc[ct][ntl][j] + pb;
                hr[n] = f2h(h);
                s += h; q = fmaf(h, h, q);
            }
            #pragma unroll
            for (int e = 1; e < 16; e <<= 1){ s += __shfl_xor(s, e); q += __shfl_xor(q, e); }
            if (lrow == 0){
                sred[0][w][co] = s;
                sred[1][w][co] = q;
            }
        }
    }
    __syncthreads();
    if (t < 64){
        float S = 0.f, Q = 0.f;
        #pragma unroll
        for (int ww = 0; ww < 4; ++ww){ S += sred[0][ww][t]; Q += sred[1][ww][t]; }
        atomicAdd(statsr + (size_t)(b*64+t)*2,     S);
        atomicAdd(statsr + (size_t)(b*64+t)*2 + 1, Q);
    }
}

// ---------------- projection head (8 waves, 8 tiles per wave) ----------------
// grid (128 b, 8 ntg of 512 n), 512 thr. A/bias/w2 loaded once per 128 cols.
__global__ __launch_bounds__(512) void k_proj(
        const unsigned short* __restrict__ xT, const unsigned short* __restrict__ w1h,
        const float* __restrict__ b1, const float* __restrict__ w2,
        const float* __restrict__ b2, float* __restrict__ out)
{
    int b = blockIdx.x, ntg = blockIdx.y;
    int t = threadIdx.x, w = t >> 6, lane = t & 63;
    int lrow = lane & 15, g = lane >> 4;
    int o2h = w & 1, nq = w >> 1;
    int nb = ntg*512 + nq*128;

    half8 A[4][2];
    #pragma unroll
    for (int ot = 0; ot < 4; ++ot)
        #pragma unroll
        for (int ks = 0; ks < 2; ++ks)
            A[ot][ks] = *(const half8*)(w1h + (size_t)(o2h*64 + ot*16 + lrow)*64 + ks*32 + g*8);
    float bb[16], wv[16];
    #pragma unroll
    for (int ot = 0; ot < 4; ++ot)
        #pragma unroll
        for (int j = 0; j < 4; ++j){
            int o2 = o2h*64 + ot*16 + g*4 + j;
            bb[ot*4+j] = b1[o2];
            wv[ot*4+j] = w2[o2];
        }
    __shared__ float sred[4][8][2][16];
    for (int tl = 0; tl < 8; ++tl){
        int n = nb + tl*16 + lrow;
        fx4 acc[4];
        #pragma unroll
        for (int i = 0; i < 4; ++i) acc[i] = (fx4){0.f,0.f,0.f,0.f};
        #pragma unroll
        for (int ks = 0; ks < 2; ++ks){
            half8 bf = *(const half8*)(xT + ((size_t)b*4096 + n)*64 + ks*32 + g*8);
            #pragma unroll
            for (int ot = 0; ot < 4; ++ot)
                acc[ot] = __builtin_amdgcn_mfma_f32_16x16x32_f16(A[ot][ks], bf, acc[ot], 0, 0, 0);
        }
        float p = 0.f;
        #pragma unroll
        for (int ot = 0; ot < 4; ++ot)
            #pragma unroll
            for (int j = 0; j < 4; ++j)
                p = fmaf(wv[ot*4+j], gelu_f(acc[ot][j] + bb[ot*4+j]), p);
        p += __shfl_xor(p, 16); p += __shfl_xor(p, 32);
        if (lane < 16) sred[nq][tl][o2h][lane] = p;
    }
    __syncthreads();
    {
        int cl = t & 15, tlf = (t >> 4) & 7, nqf = t >> 7;
        out[(size_t)b*4096 + ntg*512 + t] =
            sred[nqf][tlf][0][cl] + sred[nqf][tlf][1][cl] + b2[0];
    }
}

// ---------------- launch ----------------
extern "C" void kernel_launch(void* const* d_in, const int* in_sizes, int n_in,
                              void* d_out, int out_size, void* d_ws, size_t ws_size,
                              hipStream_t stream) {
    (void)in_sizes; (void)n_in; (void)out_size; (void)ws_size;
    const float* z      = (const float*)d_in[0];
    const float* instp  = (const float*)d_in[1];
    const float* lift_w = (const float*)d_in[2];
    const float* lift_b = (const float*)d_in[3];
    const float* iw1    = (const float*)d_in[4];
    const float* ib1    = (const float*)d_in[5];
    const float* iw2    = (const float*)d_in[6];
    const float* ib2    = (const float*)d_in[7];
    const float* specw  = (const float*)d_in[8];
    const float* pww    = (const float*)d_in[9];
    const float* pwb    = (const float*)d_in[10];
    const float* pj1w   = (const float*)d_in[11];
    const float* pj1b   = (const float*)d_in[12];
    const float* pj2w   = (const float*)d_in[13];
    const float* pj2b   = (const float*)d_in[14];

    float* ws = (float*)d_ws;
    unsigned short* xh    = (unsigned short*)(ws + OFF_XH);
    unsigned short* xT    = (unsigned short*)(ws + OFF_XT);
    unsigned short* tabB  = (unsigned short*)(ws + OFF_TABB);
    unsigned short* tabT  = (unsigned short*)(ws + OFF_TABT);
    unsigned short* mah   = (unsigned short*)(ws + OFF_MAH);
    unsigned short* pwwh  = (unsigned short*)(ws + OFF_PWWH);
    unsigned short* w1h   = (unsigned short*)(ws + OFF_W1H);
    float* cond   = ws + OFF_COND;
    float* statsr = ws + OFF_STATS;
    float* dftp   = ws + OFF_DFTP;
    float* out    = (float*)d_out;

    k_tab <<<dim3(1024),  dim3(256), 0, stream>>>(tabB, tabT, pww, pwwh, pj1w, w1h);
    k_cond<<<dim3(128),   dim3(64),  0, stream>>>(instp, iw1, ib1, iw2, ib2, cond);
    k_lift<<<dim3(64, 8), dim3(256), 0, stream>>>(z, lift_w, lift_b, cond, xh);

    for (int l = 0; l < 4; ++l){
        if (l == 0)
            k_prep<0,1><<<dim3(128,8), dim3(256), 0, stream>>>(xh, statsr, tabB, xT, dftp);
        else
            k_prep<1,1><<<dim3(128,8), dim3(256), 0, stream>>>(xh, statsr, tabB, xT, dftp);
        k_mix  <<<dim3(128),    dim3(256), 0, stream>>>(dftp, specw, mah, statsr, l);
        k_pass3<<<dim3(128,16), dim3(256), 0, stream>>>(xT, tabT, pwwh, pwb, mah, xh, statsr, l);
    }
    k_prep<1,0><<<dim3(128,8), dim3(256), 0, stream>>>(xh, statsr, tabB, xT, dftp);
    k_proj    <<<dim3(128,8),  dim3(512), 0, stream>>>(xT, w1h, pj1b, pj2w, pj2b, out);
}

// Round 8
// 586.925 us; speedup vs baseline: 2.8817x; 1.0289x over previous
//
#include <hip/hip_runtime.h>
#include <math.h>

// B=128, W=64, L=4096, MODES=32, N_LAYERS=4

typedef _Float16 half8 __attribute__((ext_vector_type(8)));  // 8 fp16 (4 VGPR)
typedef __attribute__((ext_vector_type(4))) float fx4;       // MFMA f32 acc

// fast gelu: tanh/sigmoid form, exp2-folded. gelu(x) ~= x * sigmoid(2y),
// 2y*log2e = x*(2.3022083 + 0.1029443*x^2). Max dev from exact-erf ~5e-4.
__device__ __forceinline__ float gelu_f(float x){
    float u = x*x;
    float a = x * fmaf(-0.1029443f, u, -2.3022083f);   // -2y*log2(e)
    float e = exp2f(a);                                 // e^{-2y}
    float r = __builtin_amdgcn_rcpf(1.0f + e);          // sigmoid(2y)
    return x * r;
}
__device__ __forceinline__ unsigned short f2h(float f){
    union { _Float16 h; unsigned short u; } c;
    c.h = (_Float16)f;
    return c.u;
}
__device__ __forceinline__ float h2f(unsigned short u){
    union { unsigned short u; _Float16 h; } c;
    c.u = u;
    return (float)c.h;
}

// ---------------- workspace layout (float-slot offsets) ----------------
// xh    : fp16 [128][64][4096]  h / x0 (channel-major)
// xT    : fp16 [128][4096][64]  normalized x, position-major
// tabB  : fp16 [64][4096]       rows 0-31 cos, 32-63 sin (fwd DFT)
// tabT  : fp16 [4096][64]       transpose, scaled 1/64 (iDFT)
// mah   : fp16 [b][co][64]      iDFT coeffs x64
// pwwh  : fp16 [4][64][64]
// w1h   : fp16 [128][64]
// cond  : f32  [b][64]
// statsr: f32  [b][co][2]       RAW (S, Q) accumulated by pass3 atomics
// dftp  : f32  [b][8][64 ci][64 m2]   (ci-major, m2 contiguous)
static const size_t OFF_XH    = 0;
static const size_t OFF_XT    = 16777216;
static const size_t OFF_TABB  = 33554432;
static const size_t OFF_TABT  = 33685504;
static const size_t OFF_MAH   = 33816576;   // 262,144 slots
static const size_t OFF_PWWH  = 34078720;   // 8,192
static const size_t OFF_W1H   = 34086912;   // 4,096
static const size_t OFF_COND  = 34091008;   // 8,192
static const size_t OFF_STATS = 34099200;   // 16,384
static const size_t OFF_DFTP  = 34115584;   // 4,194,304
// end = 38,309,888 slots = 153 MB (< proven 157.4 MB footprint)

// ---------------- trig tables + weight fp16 conversion ----------------
__global__ void k_tab(unsigned short* __restrict__ tabB, unsigned short* __restrict__ tabT,
                      const float* __restrict__ pww, unsigned short* __restrict__ pwwh,
                      const float* __restrict__ pj1w, unsigned short* __restrict__ w1h){
    int t = blockIdx.x*256 + threadIdx.x;        // 262144
    if (t < 16384) pwwh[t] = f2h(pww[t]);
    if (t < 8192)  w1h[t]  = f2h(pj1w[t]);
    int m2 = t >> 12, n = t & 4095;
    int m = m2 & 31;
    int r = (m*n) & 4095;
    int r2 = (r >= 2048) ? (r - 4096) : r;       // fold to [-pi, pi)
    float a = (float)r2 * 1.5339807878856412e-3f;   // 2*pi/4096
    float v = (m2 >= 32) ? sinf(a) : cosf(a);
    tabB[(size_t)m2*4096 + n] = f2h(v);
    tabT[(size_t)n*64 + m2]   = f2h(v * 0.015625f);
}

// ---------------- conditioning MLP ----------------
__global__ __launch_bounds__(64) void k_cond(const float* __restrict__ instp,
        const float* __restrict__ w1, const float* __restrict__ b1,
        const float* __restrict__ w2, const float* __restrict__ b2,
        float* __restrict__ cond){
    int b = blockIdx.x, tid = threadIdx.x;
    __shared__ float ipl[8];
    __shared__ float tl[64];
    if (tid < 8) ipl[tid] = instp[b*8 + tid];
    __syncthreads();
    float s = b1[tid];
    #pragma unroll
    for (int k = 0; k < 8; ++k) s = fmaf(ipl[k], w1[k*64 + tid], s);
    tl[tid] = gelu_f(s);
    __syncthreads();
    float c = b2[tid];
    #pragma unroll 8
    for (int j = 0; j < 64; ++j) c = fmaf(tl[j], w2[j*64 + tid], c);
    cond[b*64 + tid] = c;
}

// ---------------- lift + interp + cond -> xh (fp16) ----------------
// grid (64 wc, 8 bg), 256 thr. lift_w column-block staged ONCE per block.
__global__ __launch_bounds__(256) void k_lift(const float* __restrict__ z,
        const float* __restrict__ lw, const float* __restrict__ lb,
        const float* __restrict__ cond, unsigned short* __restrict__ xh){
    int wc = blockIdx.x;
    int b0 = blockIdx.y * 16;
    int t = threadIdx.x;
    __shared__ float lwl[128*64];   // [d][pos]
    __shared__ float zl[16*128];    // [bb][d]
    __shared__ float x0[16*64];     // [bb][pos]
    #pragma unroll
    for (int i = 0; i < 32; ++i){
        int idx = i*256 + t;
        lwl[idx] = lw[(size_t)(idx >> 6)*4096 + wc*64 + (idx & 63)];
    }
    #pragma unroll
    for (int i = 0; i < 8; ++i){
        int idx = i*256 + t;
        zl[idx] = z[(b0 + (idx >> 7))*128 + (idx & 127)];
    }
    __syncthreads();
    #pragma unroll
    for (int i = 0; i < 4; ++i){
        int idx = i*256 + t;
        int bb = idx >> 6, pos = idx & 63;
        float s = 0.f;
        #pragma unroll 8
        for (int d = 0; d < 128; ++d)
            s = fmaf(zl[bb*128 + d], lwl[d*64 + pos], s);
        // cond is per-CHANNEL (wc), broadcast over positions
        x0[idx] = s + lb[wc*64 + pos] + cond[(b0 + bb)*64 + wc];
    }
    __syncthreads();
    for (int bb = 0; bb < 16; ++bb){
        const float* xr = x0 + bb*64;
        unsigned int pk[8];
        #pragma unroll
        for (int i = 0; i < 8; ++i){
            float v[2];
            #pragma unroll
            for (int q = 0; q < 2; ++q){
                int n = t*16 + i*2 + q;
                float src = (n + 0.5f)*0.015625f - 0.5f;
                src = fminf(fmaxf(src, 0.0f), 63.0f);
                int i0 = (int)src;
                int i1 = (i0 + 1 > 63) ? 63 : (i0 + 1);
                float wt = src - (float)i0;
                v[q] = xr[i0] + wt*(xr[i1] - xr[i0]);
            }
            pk[i] = (unsigned int)f2h(v[0]) | ((unsigned int)f2h(v[1]) << 16);
        }
        unsigned short* dst = xh + ((size_t)((b0 + bb)*64 + wc))*4096 + t*16;
        *(uint4*)dst       = make_uint4(pk[0],pk[1],pk[2],pk[3]);
        *(uint4*)(dst + 8) = make_uint4(pk[4],pk[5],pk[6],pk[7]);
    }
}

// ---------------- prep: norm+gelu -> x, transpose-store xT, forward-DFT ----------------
// double-buffered LDS tile, ONE barrier per iter, global loads prefetched 1 iter ahead.
template<int NORM, int DODFT>
__global__ __launch_bounds__(256) void k_prep(
        const unsigned short* __restrict__ xhp, const float* __restrict__ statsr,
        const unsigned short* __restrict__ tabB, unsigned short* __restrict__ xT,
        float* __restrict__ dftp)
{
    int b = blockIdx.x, ng = blockIdx.y;
    int t = threadIdx.x;
    int w = t >> 6, lane = t & 63;
    int lrow = lane & 15, g = lane >> 4;
    __shared__ __align__(16) unsigned short xl[2][4096];
    int co = t >> 2, nq = t & 3;
    float mu = 0.f, rs = 1.f;
    if (NORM){
        float2 sr = *(const float2*)(statsr + (size_t)(b*64+co)*2);
        mu = sr.x * (1.f/4096.f);
        float var = fmaf(sr.y, 1.f/4096.f, -mu*mu);
        rs = rsqrtf(var + 1e-5f);
    }
    fx4 acc[4];
    #pragma unroll
    for (int i = 0; i < 4; ++i) acc[i] = (fx4){0.f,0.f,0.f,0.f};

    const unsigned short* hrow = xhp + ((size_t)(b*64+co))*4096 + ng*512 + nq*16;
    unsigned short* xtbase = xT + ((size_t)b*4096 + (size_t)ng*512)*64;

    uint4 cA = *(const uint4*)(hrow);
    uint4 cB = *(const uint4*)(hrow + 8);
    for (int it = 0; it < 8; ++it){
        int n0 = ng*512 + it*64;
        char* xb = (char*)(&xl[it & 1][0]);
        uint4 nA, nB;
        if (it < 7){                                  // prefetch next iter's tile
            nA = *(const uint4*)(hrow + (it+1)*64);
            nB = *(const uint4*)(hrow + (it+1)*64 + 8);
        }
        unsigned int pk[8];
        if (NORM){
            unsigned int hu[8] = {cA.x,cA.y,cA.z,cA.w,cB.x,cB.y,cB.z,cB.w};
            #pragma unroll
            for (int i = 0; i < 8; ++i){
                float f0 = h2f((unsigned short)(hu[i] & 0xFFFFu));
                float f1 = h2f((unsigned short)(hu[i] >> 16));
                f0 = gelu_f((f0 - mu)*rs);
                f1 = gelu_f((f1 - mu)*rs);
                pk[i] = (unsigned int)f2h(f0) | ((unsigned int)f2h(f1) << 16);
            }
        } else {
            pk[0]=cA.x; pk[1]=cA.y; pk[2]=cA.z; pk[3]=cA.w;
            pk[4]=cB.x; pk[5]=cB.y; pk[6]=cB.z; pk[7]=cB.w;
        }
        unsigned int base = (unsigned int)co*128 + (unsigned int)nq*32;
        unsigned int sw = (unsigned int)((co & 7) << 4);
        *(uint4*)(xb + ((base +  0) ^ sw)) = make_uint4(pk[0],pk[1],pk[2],pk[3]);
        *(uint4*)(xb + ((base + 16) ^ sw)) = make_uint4(pk[4],pk[5],pk[6],pk[7]);
        __syncthreads();

        if (DODFT){
            int m0 = w*16;
            #pragma unroll
            for (int ks = 0; ks < 2; ++ks){
                int kk = ks*32 + g*8;
                half8 af = *(const half8*)(tabB + (size_t)(m0 + lrow)*4096 + n0 + kk);
                #pragma unroll
                for (int ct = 0; ct < 4; ++ct){
                    int row = ct*16 + lrow;
                    unsigned int ba = ((unsigned int)row*128 + (unsigned int)kk*2)
                                      ^ (unsigned int)((row & 7) << 4);
                    half8 bf = *(const half8*)(xb + ba);
                    acc[ct] = __builtin_amdgcn_mfma_f32_16x16x32_f16(af, bf, acc[ct], 0, 0, 0);
                }
            }
        }
        {   // transpose out: xT[b][n][co]
            int n = t & 63, coq = t >> 6;
            unsigned int opk[8];
            #pragma unroll
            for (int i = 0; i < 8; ++i){
                int r0 = coq*16 + 2*i, r1 = r0 + 1;
                unsigned int a0 = ((unsigned int)r0*128 + (unsigned int)n*2)
                                  ^ (unsigned int)((r0 & 7) << 4);
                unsigned int a1 = ((unsigned int)r1*128 + (unsigned int)n*2)
                                  ^ (unsigned int)((r1 & 7) << 4);
                unsigned short v0 = *(const unsigned short*)(xb + a0);
                unsigned short v1 = *(const unsigned short*)(xb + a1);
                opk[i] = (unsigned int)v0 | ((unsigned int)v1 << 16);
            }
            unsigned short* dst = xtbase + (size_t)(it*64 + n)*64 + coq*16;
            *(uint4*)dst       = make_uint4(opk[0],opk[1],opk[2],opk[3]);
            *(uint4*)(dst + 8) = make_uint4(opk[4],opk[5],opk[6],opk[7]);
        }
        if (it < 7){ cA = nA; cB = nB; }
        // no second barrier: next iter writes the other LDS buffer; the
        // waitcnt before the next s_barrier drains this iter's LDS reads
    }
    if (DODFT){
        // dftp layout [b][ng][ci][m2]: j is contiguous -> float4 stores
        int m0 = w*16;
        #pragma unroll
        for (int ct = 0; ct < 4; ++ct){
            float4 v = make_float4(acc[ct][0], acc[ct][1], acc[ct][2], acc[ct][3]);
            *(float4*)(dftp + ((size_t)(b*8+ng)*64 + ct*16 + lrow)*64 + m0 + g*4) = v;
        }
    }
}

// ---------------- spectral mix (fused dftred + stats zero) ----------------
// grid (128 b), 256 thr. dftp is [ng][ci][m2].
__global__ __launch_bounds__(256) void k_mix(const float* __restrict__ dftp,
        const float* __restrict__ specw, unsigned short* __restrict__ mah,
        float* __restrict__ statsr, int l){
    int b = blockIdx.x, t = threadIdx.x;
    __shared__ float xm[4096];               // [32 m][64 ci][2]
    if (t < 128) statsr[b*128 + t] = 0.f;    // zero raw stats for this layer's pass3
    const float* dp = dftp + (size_t)b*8*4096;
    #pragma unroll
    for (int i = 0; i < 16; ++i){
        int e = i*256 + t;                   // e = ci*64 + m2
        float s = 0.f;
        #pragma unroll
        for (int ng = 0; ng < 8; ++ng) s += dp[ng*4096 + e];
        int ci = e >> 6, m2 = e & 63;
        if (m2 < 32) xm[(m2*64 + ci)*2] = s;           // Xr
        else         xm[((m2-32)*64 + ci)*2 + 1] = -s; // Xi = -sum(sin)
    }
    __syncthreads();
    int co = t >> 2, mq = t & 3;
    float yr[8] = {0,0,0,0,0,0,0,0}, yi[8] = {0,0,0,0,0,0,0,0};
    const float* wbase = specw + (size_t)(l*64)*4096 + co*64 + mq*16;
    for (int ci = 0; ci < 64; ++ci){
        const float* wp = wbase + (size_t)ci*4096;
        float4 w0 = *(const float4*)(wp);
        float4 w1v = *(const float4*)(wp + 4);
        float4 w2v = *(const float4*)(wp + 8);
        float4 w3v = *(const float4*)(wp + 12);
        float wr[8] = {w0.x,w0.z,w1v.x,w1v.z,w2v.x,w2v.z,w3v.x,w3v.z};
        float wi[8] = {w0.y,w0.w,w1v.y,w1v.w,w2v.y,w2v.w,w3v.y,w3v.w};
        #pragma unroll
        for (int mm = 0; mm < 8; ++mm){
            int m = mq*8 + mm;
            float2 x = *(const float2*)(xm + (m*64 + ci)*2);
            yr[mm] = fmaf(x.x, wr[mm], fmaf(-x.y, wi[mm], yr[mm]));
            yi[mm] = fmaf(x.x, wi[mm], fmaf( x.y, wr[mm], yi[mm]));
        }
    }
    unsigned short* mb = mah + (size_t)(b*64 + co)*64;
    #pragma unroll
    for (int mm = 0; mm < 8; ++mm){
        int m = mq*8 + mm;
        float sc = (m == 0) ? 0.015625f : 0.03125f;   // (1|2)/4096 * 64
        mb[m]      = f2h(sc * yr[mm]);
        mb[32 + m] = f2h(-0.03125f * yi[mm]);
    }
}

// ---------------- fused pointwise + iDFT (MFMA, SWAPPED operands) ----------------
// Computes H^T tiles: A = [x | tab] (M=n, K=ci), B = [W ; ma]^T (K=ci, N=co).
// D layout: col(lane&15)=co, row(g*4+j)=n -> each lane holds 4 CONSECUTIVE n
// for fixed co -> h stores are uint2 (4x fewer store instructions).
__global__ __launch_bounds__(256, 2) void k_pass3(
        const unsigned short* __restrict__ xT, const unsigned short* __restrict__ tabT,
        const unsigned short* __restrict__ pwwh, const float* __restrict__ pwb,
        const unsigned short* __restrict__ mah, unsigned short* __restrict__ xh,
        float* __restrict__ statsr, int lay)
{
    int b = blockIdx.x, ntg = blockIdx.y;
    int t = threadIdx.x, w = t >> 6, lane = t & 63;
    int lrow = lane & 15, g = lane >> 4;
    int nsl = ntg*256 + w*64;                // this wave's 64-n slab

    half8 A[4][4];                           // [nt][ks]: rows = n, k-octet g
    #pragma unroll
    for (int nt = 0; nt < 4; ++nt){
        int n = nsl + nt*16 + lrow;
        #pragma unroll
        for (int ks = 0; ks < 4; ++ks){
            int k = ks*32 + g*8;
            const unsigned short* src = (k < 64)
                ? (xT   + ((size_t)b*4096 + n)*64 + k)
                : (tabT + (size_t)n*64 + (k - 64));
            A[nt][ks] = *(const half8*)src;
        }
    }
    half8 Bv[4][4];                          // [cot][ks]: cols = co
    #pragma unroll
    for (int cot = 0; cot < 4; ++cot){
        int co = cot*16 + lrow;
        #pragma unroll
        for (int ks = 0; ks < 4; ++ks){
            int k = ks*32 + g*8;
            const unsigned short* src = (k < 64)
                ? (pwwh + ((size_t)lay*64 + co)*64 + k)
                : (mah  + ((size_t)b*64 + co)*64 + (k - 64));
            Bv[cot][ks] = *(const half8*)src;
        }
    }
    fx4 acc[4][4];                           // [nt][cot]
    #pragma unroll
    for (int i = 0; i < 4; ++i)
        #pragma unroll
        for (int j = 0; j < 4; ++j) acc[i][j] = (fx4){0.f,0.f,0.f,0.f};

    #pragma unroll
    for (int ks = 0; ks < 4; ++ks)
        #pragma unroll
        for (int nt = 0; nt < 4; ++nt)
            #pragma unroll
            for (int cot = 0; cot < 4; ++cot)
                acc[nt][cot] = __builtin_amdgcn_mfma_f32_16x16x32_f16(A[nt][ks], Bv[cot][ks], acc[nt][cot], 0, 0, 0);

    // epilogue: +bias, packed uint2 stores, per-cot stats
    float sS[4] = {0,0,0,0}, sQ[4] = {0,0,0,0};
    #pragma unroll
    for (int cot = 0; cot < 4; ++cot){
        int co = cot*16 + lrow;
        float pb = pwb[lay*64 + co];
        unsigned short* hr = xh + ((size_t)(b*64+co))*4096;
        #pragma unroll
        for (int nt = 0; nt < 4; ++nt){
            float h0 = acc[nt][cot][0] + pb;
            float h1 = acc[nt][cot][1] + pb;
            float h2 = acc[nt][cot][2] + pb;
            float h3 = acc[nt][cot][3] + pb;
            uint2 pk;
            pk.x = (unsigned int)f2h(h0) | ((unsigned int)f2h(h1) << 16);
            pk.y = (unsigned int)f2h(h2) | ((unsigned int)f2h(h3) << 16);
            *(uint2*)(hr + nsl + nt*16 + g*4) = pk;
            sS[cot] += (h0 + h1) + (h2 + h3);
            float q = h0*h0;
            q = fmaf(h1, h1, q); q = fmaf(h2, h2, q); q = fmaf(h3, h3, q);
            sQ[cot] += q;
        }
    }
    __shared__ float sred[2][4][64];
    #pragma unroll
    for (int cot = 0; cot < 4; ++cot){
        float s = sS[cot], q = sQ[cot];
        s += __shfl_xor(s, 16); q += __shfl_xor(q, 16);
        s += __shfl_xor(s, 32); q += __shfl_xor(q, 32);
        if (g == 0){
            sred[0][w][cot*16 + lrow] = s;
            sred[1][w][cot*16 + lrow] = q;
        }
    }
    __syncthreads();
    if (t < 64){
        float S = 0.f, Q = 0.f;
        #pragma unroll
        for (int ww = 0; ww < 4; ++ww){ S += sred[0][ww][t]; Q += sred[1][ww][t]; }
        atomicAdd(statsr + (size_t)(b*64+t)*2,     S);
        atomicAdd(statsr + (size_t)(b*64+t)*2 + 1, Q);
    }
}

// ---------------- projection head (8 waves, 8 tiles per wave) ----------------
// grid (128 b, 8 ntg of 512 n), 512 thr. A/bias/w2 loaded once per 128 cols.
__global__ __launch_bounds__(512) void k_proj(
        const unsigned short* __restrict__ xT, const unsigned short* __restrict__ w1h,
        const float* __restrict__ b1, const float* __restrict__ w2,
        const float* __restrict__ b2, float* __restrict__ out)
{
    int b = blockIdx.x, ntg = blockIdx.y;
    int t = threadIdx.x, w = t >> 6, lane = t & 63;
    int lrow = lane & 15, g = lane >> 4;
    int o2h = w & 1, nq = w >> 1;
    int nb = ntg*512 + nq*128;

    half8 A[4][2];
    #pragma unroll
    for (int ot = 0; ot < 4; ++ot)
        #pragma unroll
        for (int ks = 0; ks < 2; ++ks)
            A[ot][ks] = *(const half8*)(w1h + (size_t)(o2h*64 + ot*16 + lrow)*64 + ks*32 + g*8);
    float bb[16], wv[16];
    #pragma unroll
    for (int ot = 0; ot < 4; ++ot)
        #pragma unroll
        for (int j = 0; j < 4; ++j){
            int o2 = o2h*64 + ot*16 + g*4 + j;
            bb[ot*4+j] = b1[o2];
            wv[ot*4+j] = w2[o2];
        }
    __shared__ float sred[4][8][2][16];
    for (int tl = 0; tl < 8; ++tl){
        int n = nb + tl*16 + lrow;
        fx4 acc[4];
        #pragma unroll
        for (int i = 0; i < 4; ++i) acc[i] = (fx4){0.f,0.f,0.f,0.f};
        #pragma unroll
        for (int ks = 0; ks < 2; ++ks){
            half8 bf = *(const half8*)(xT + ((size_t)b*4096 + n)*64 + ks*32 + g*8);
            #pragma unroll
            for (int ot = 0; ot < 4; ++ot)
                acc[ot] = __builtin_amdgcn_mfma_f32_16x16x32_f16(A[ot][ks], bf, acc[ot], 0, 0, 0);
        }
        float p = 0.f;
        #pragma unroll
        for (int ot = 0; ot < 4; ++ot)
            #pragma unroll
            for (int j = 0; j < 4; ++j)
                p = fmaf(wv[ot*4+j], gelu_f(acc[ot][j] + bb[ot*4+j]), p);
        p += __shfl_xor(p, 16); p += __shfl_xor(p, 32);
        if (lane < 16) sred[nq][tl][o2h][lane] = p;
    }
    __syncthreads();
    {
        int cl = t & 15, tlf = (t >> 4) & 7, nqf = t >> 7;
        out[(size_t)b*4096 + ntg*512 + t] =
            sred[nqf][tlf][0][cl] + sred[nqf][tlf][1][cl] + b2[0];
    }
}

// ---------------- launch ----------------
extern "C" void kernel_launch(void* const* d_in, const int* in_sizes, int n_in,
                              void* d_out, int out_size, void* d_ws, size_t ws_size,
                              hipStream_t stream) {
    (void)in_sizes; (void)n_in; (void)out_size; (void)ws_size;
    const float* z      = (const float*)d_in[0];
    const float* instp  = (const float*)d_in[1];
    const float* lift_w = (const float*)d_in[2];
    const float* lift_b = (const float*)d_in[3];
    const float* iw1    = (const float*)d_in[4];
    const float* ib1    = (const float*)d_in[5];
    const float* iw2    = (const float*)d_in[6];
    const float* ib2    = (const float*)d_in[7];
    const float* specw  = (const float*)d_in[8];
    const float* pww    = (const float*)d_in[9];
    const float* pwb    = (const float*)d_in[10];
    const float* pj1w   = (const float*)d_in[11];
    const float* pj1b   = (const float*)d_in[12];
    const float* pj2w   = (const float*)d_in[13];
    const float* pj2b   = (const float*)d_in[14];

    float* ws = (float*)d_ws;
    unsigned short* xh    = (unsigned short*)(ws + OFF_XH);
    unsigned short* xT    = (unsigned short*)(ws + OFF_XT);
    unsigned short* tabB  = (unsigned short*)(ws + OFF_TABB);
    unsigned short* tabT  = (unsigned short*)(ws + OFF_TABT);
    unsigned short* mah   = (unsigned short*)(ws + OFF_MAH);
    unsigned short* pwwh  = (unsigned short*)(ws + OFF_PWWH);
    unsigned short* w1h   = (unsigned short*)(ws + OFF_W1H);
    float* cond   = ws + OFF_COND;
    float* statsr = ws + OFF_STATS;
    float* dftp   = ws + OFF_DFTP;
    float* out    = (float*)d_out;

    k_tab <<<dim3(1024),  dim3(256), 0, stream>>>(tabB, tabT, pww, pwwh, pj1w, w1h);
    k_cond<<<dim3(128),   dim3(64),  0, stream>>>(instp, iw1, ib1, iw2, ib2, cond);
    k_lift<<<dim3(64, 8), dim3(256), 0, stream>>>(z, lift_w, lift_b, cond, xh);

    for (int l = 0; l < 4; ++l){
        if (l == 0)
            k_prep<0,1><<<dim3(128,8), dim3(256), 0, stream>>>(xh, statsr, tabB, xT, dftp);
        else
            k_prep<1,1><<<dim3(128,8), dim3(256), 0, stream>>>(xh, statsr, tabB, xT, dftp);
        k_mix  <<<dim3(128),    dim3(256), 0, stream>>>(dftp, specw, mah, statsr, l);
        k_pass3<<<dim3(128,16), dim3(256), 0, stream>>>(xT, tabT, pwwh, pwb, mah, xh, statsr, l);
    }
    k_prep<1,0><<<dim3(128,8), dim3(256), 0, stream>>>(xh, statsr, tabB, xT, dftp);
    k_proj    <<<dim3(128,8),  dim3(512), 0, stream>>>(xT, w1h, pj1b, pj2w, pj2b, out);
}

// Round 9
// 560.496 us; speedup vs baseline: 3.0176x; 1.0472x over previous
//
#include <hip/hip_runtime.h>
#include <math.h>

// B=128, W=64, L=4096, MODES=32, N_LAYERS=4

typedef _Float16 half8 __attribute__((ext_vector_type(8)));  // 8 fp16 (4 VGPR)
typedef __attribute__((ext_vector_type(4))) float fx4;       // MFMA f32 acc

// fast gelu: tanh/sigmoid form, exp2-folded. Max dev from exact-erf ~5e-4.
__device__ __forceinline__ float gelu_f(float x){
    float u = x*x;
    float a = x * fmaf(-0.1029443f, u, -2.3022083f);   // -2y*log2(e)
    float e = exp2f(a);                                 // e^{-2y}
    float r = __builtin_amdgcn_rcpf(1.0f + e);          // sigmoid(2y)
    return x * r;
}
__device__ __forceinline__ unsigned short f2h(float f){
    union { _Float16 h; unsigned short u; } c;
    c.h = (_Float16)f;
    return c.u;
}
__device__ __forceinline__ float h2f(unsigned short u){
    union { unsigned short u; _Float16 h; } c;
    c.u = u;
    return (float)c.h;
}

// ---------------- workspace layout (float-slot offsets) ----------------
// xh    : fp16 [128][64][4096]  h (channel-major); layer-0 input never materialized
// xT    : fp16 [128][4096][64]  normalized x, position-major
// tabB  : fp16 [64][4096]       rows 0-31 cos, 32-63 sin (fwd DFT)
// tabT  : fp16 [4096][64]       transpose, scaled 1/64 (iDFT)
// mah   : fp16 [b][co][64]      iDFT coeffs x64
// pwwh  : fp16 [4][64][64]
// w1h   : fp16 [128][64]
// cond  : f32  [b][64]
// statsr: f32  [b][co][2]       RAW (S, Q) accumulated by pass3 atomics
// dftp  : f32  [b][8][64 ci][64 m2]
// x0    : f32  [b][64 wc][64 pos]  lift output (pre-interp)
static const size_t OFF_XH    = 0;
static const size_t OFF_XT    = 16777216;
static const size_t OFF_TABB  = 33554432;
static const size_t OFF_TABT  = 33685504;
static const size_t OFF_MAH   = 33816576;   // 262,144 slots
static const size_t OFF_PWWH  = 34078720;   // 8,192
static const size_t OFF_W1H   = 34086912;   // 4,096
static const size_t OFF_COND  = 34091008;   // 8,192
static const size_t OFF_STATS = 34099200;   // 16,384
static const size_t OFF_DFTP  = 34115584;   // 4,194,304
static const size_t OFF_X0    = 38309888;   // 524,288
// end = 38,834,176 slots = 155.3 MB (< proven 157.4 MB footprint)

// ---------------- trig tables + weight fp16 conversion ----------------
__global__ void k_tab(unsigned short* __restrict__ tabB, unsigned short* __restrict__ tabT,
                      const float* __restrict__ pww, unsigned short* __restrict__ pwwh,
                      const float* __restrict__ pj1w, unsigned short* __restrict__ w1h){
    int t = blockIdx.x*256 + threadIdx.x;        // 262144
    if (t < 16384) pwwh[t] = f2h(pww[t]);
    if (t < 8192)  w1h[t]  = f2h(pj1w[t]);
    int m2 = t >> 12, n = t & 4095;
    int m = m2 & 31;
    int r = (m*n) & 4095;
    int r2 = (r >= 2048) ? (r - 4096) : r;       // fold to [-pi, pi)
    float a = (float)r2 * 1.5339807878856412e-3f;   // 2*pi/4096
    float v = (m2 >= 32) ? sinf(a) : cosf(a);
    tabB[(size_t)m2*4096 + n] = f2h(v);
    tabT[(size_t)n*64 + m2]   = f2h(v * 0.015625f);
}

// ---------------- conditioning MLP ----------------
__global__ __launch_bounds__(64) void k_cond(const float* __restrict__ instp,
        const float* __restrict__ w1, const float* __restrict__ b1,
        const float* __restrict__ w2, const float* __restrict__ b2,
        float* __restrict__ cond){
    int b = blockIdx.x, tid = threadIdx.x;
    __shared__ float ipl[8];
    __shared__ float tl[64];
    if (tid < 8) ipl[tid] = instp[b*8 + tid];
    __syncthreads();
    float s = b1[tid];
    #pragma unroll
    for (int k = 0; k < 8; ++k) s = fmaf(ipl[k], w1[k*64 + tid], s);
    tl[tid] = gelu_f(s);
    __syncthreads();
    float c = b2[tid];
    #pragma unroll 8
    for (int j = 0; j < 64; ++j) c = fmaf(tl[j], w2[j*64 + tid], c);
    cond[b*64 + tid] = c;
}

// ---------------- lift core: x0 = z @ lift_w + lb + cond (f32, 2 MB) ----------------
// grid (128 b, 4 q), 256 thr.
__global__ __launch_bounds__(256) void k_liftc(const float* __restrict__ z,
        const float* __restrict__ lw, const float* __restrict__ lb,
        const float* __restrict__ cond, float* __restrict__ x0){
    int b = blockIdx.x, q = blockIdx.y;
    int t = threadIdx.x;
    __shared__ float zl[128];
    if (t < 128) zl[t] = z[b*128 + t];
    __syncthreads();
    #pragma unroll
    for (int i = 0; i < 4; ++i){
        int e = q*1024 + i*256 + t;            // e = wc*64 + pos
        float s = lb[e];
        #pragma unroll 8
        for (int d = 0; d < 128; ++d)
            s = fmaf(zl[d], lw[(size_t)d*4096 + e], s);
        x0[(size_t)b*4096 + e] = s + cond[b*64 + (e >> 6)];
    }
}

// ---------------- prep: (interp | norm+gelu) -> x, transpose-store xT, fwd-DFT ----------
// MODE: 1 = norm+gelu from xh; 2 = inline linear-interp from x0 (layer 0).
// double-buffered LDS tile, ONE barrier per iter, global loads prefetched 1 ahead.
template<int MODE, int DODFT>
__global__ __launch_bounds__(256) void k_prep(
        const unsigned short* __restrict__ xhp, const float* __restrict__ statsr,
        const unsigned short* __restrict__ tabB, const float* __restrict__ x0,
        unsigned short* __restrict__ xT, float* __restrict__ dftp)
{
    int b = blockIdx.x, ng = blockIdx.y;
    int t = threadIdx.x;
    int w = t >> 6, lane = t & 63;
    int lrow = lane & 15, g = lane >> 4;
    __shared__ __align__(16) unsigned short xl[2][4096];
    __shared__ float xs[(MODE == 2) ? 65*64 : 1];   // [co][64+1 pad]
    int co = t >> 2, nq = t & 3;
    float mu = 0.f, rs = 1.f;
    if (MODE == 1){
        float2 sr = *(const float2*)(statsr + (size_t)(b*64+co)*2);
        mu = sr.x * (1.f/4096.f);
        float var = fmaf(sr.y, 1.f/4096.f, -mu*mu);
        rs = rsqrtf(var + 1e-5f);
    }
    if (MODE == 2){
        const float* xb0 = x0 + (size_t)b*4096;
        #pragma unroll
        for (int i = 0; i < 16; ++i){
            int idx = i*256 + t;
            xs[(idx >> 6)*65 + (idx & 63)] = xb0[idx];
        }
        __syncthreads();
    }
    fx4 acc[4];
    #pragma unroll
    for (int i = 0; i < 4; ++i) acc[i] = (fx4){0.f,0.f,0.f,0.f};

    const unsigned short* hrow = xhp + ((size_t)(b*64+co))*4096 + ng*512 + nq*16;
    unsigned short* xtbase = xT + ((size_t)b*4096 + (size_t)ng*512)*64;

    uint4 cA, cB;
    if (MODE == 1){ cA = *(const uint4*)(hrow); cB = *(const uint4*)(hrow + 8); }
    for (int it = 0; it < 8; ++it){
        int n0 = ng*512 + it*64;
        char* xb = (char*)(&xl[it & 1][0]);
        uint4 nA, nB;
        if (MODE == 1 && it < 7){                 // prefetch next iter's tile
            nA = *(const uint4*)(hrow + (it+1)*64);
            nB = *(const uint4*)(hrow + (it+1)*64 + 8);
        }
        unsigned int pk[8];
        if (MODE == 1){
            unsigned int hu[8] = {cA.x,cA.y,cA.z,cA.w,cB.x,cB.y,cB.z,cB.w};
            #pragma unroll
            for (int i = 0; i < 8; ++i){
                float f0 = h2f((unsigned short)(hu[i] & 0xFFFFu));
                float f1 = h2f((unsigned short)(hu[i] >> 16));
                f0 = gelu_f((f0 - mu)*rs);
                f1 = gelu_f((f1 - mu)*rs);
                pk[i] = (unsigned int)f2h(f0) | ((unsigned int)f2h(f1) << 16);
            }
        } else {                                  // MODE == 2: inline interp from x0
            const float* xr = xs + co*65;
            #pragma unroll
            for (int i = 0; i < 8; ++i){
                float v[2];
                #pragma unroll
                for (int q = 0; q < 2; ++q){
                    int n = n0 + nq*16 + i*2 + q;
                    float src = (n + 0.5f)*0.015625f - 0.5f;
                    src = fminf(fmaxf(src, 0.0f), 63.0f);
                    int i0 = (int)src;
                    int i1 = (i0 + 1 > 63) ? 63 : (i0 + 1);
                    float wt = src - (float)i0;
                    v[q] = xr[i0] + wt*(xr[i1] - xr[i0]);
                }
                pk[i] = (unsigned int)f2h(v[0]) | ((unsigned int)f2h(v[1]) << 16);
            }
        }
        unsigned int base = (unsigned int)co*128 + (unsigned int)nq*32;
        unsigned int sw = (unsigned int)((co & 7) << 4);
        *(uint4*)(xb + ((base +  0) ^ sw)) = make_uint4(pk[0],pk[1],pk[2],pk[3]);
        *(uint4*)(xb + ((base + 16) ^ sw)) = make_uint4(pk[4],pk[5],pk[6],pk[7]);
        __syncthreads();

        if (DODFT){
            int m0 = w*16;
            #pragma unroll
            for (int ks = 0; ks < 2; ++ks){
                int kk = ks*32 + g*8;
                half8 af = *(const half8*)(tabB + (size_t)(m0 + lrow)*4096 + n0 + kk);
                #pragma unroll
                for (int ct = 0; ct < 4; ++ct){
                    int row = ct*16 + lrow;
                    unsigned int ba = ((unsigned int)row*128 + (unsigned int)kk*2)
                                      ^ (unsigned int)((row & 7) << 4);
                    half8 bf = *(const half8*)(xb + ba);
                    acc[ct] = __builtin_amdgcn_mfma_f32_16x16x32_f16(af, bf, acc[ct], 0, 0, 0);
                }
            }
        }
        {   // transpose out: xT[b][n][co]
            int n = t & 63, coq = t >> 6;
            unsigned int opk[8];
            #pragma unroll
            for (int i = 0; i < 8; ++i){
                int r0 = coq*16 + 2*i, r1 = r0 + 1;
                unsigned int a0 = ((unsigned int)r0*128 + (unsigned int)n*2)
                                  ^ (unsigned int)((r0 & 7) << 4);
                unsigned int a1 = ((unsigned int)r1*128 + (unsigned int)n*2)
                                  ^ (unsigned int)((r1 & 7) << 4);
                unsigned short v0 = *(const unsigned short*)(xb + a0);
                unsigned short v1 = *(const unsigned short*)(xb + a1);
                opk[i] = (unsigned int)v0 | ((unsigned int)v1 << 16);
            }
            unsigned short* dst = xtbase + (size_t)(it*64 + n)*64 + coq*16;
            *(uint4*)dst       = make_uint4(opk[0],opk[1],opk[2],opk[3]);
            *(uint4*)(dst + 8) = make_uint4(opk[4],opk[5],opk[6],opk[7]);
        }
        if (MODE == 1 && it < 7){ cA = nA; cB = nB; }
        // no second barrier: next iter writes the other LDS buffer
    }
    if (DODFT){
        // dftp layout [b][ng][ci][m2]: j contiguous -> float4 stores
        int m0 = w*16;
        #pragma unroll
        for (int ct = 0; ct < 4; ++ct){
            float4 v = make_float4(acc[ct][0], acc[ct][1], acc[ct][2], acc[ct][3]);
            *(float4*)(dftp + ((size_t)(b*8+ng)*64 + ct*16 + lrow)*64 + m0 + g*4) = v;
        }
    }
}

// ---------------- spectral mix (fused dftred + stats zero) ----------------
// grid (128 b), 256 thr. dftp is [ng][ci][m2].
__global__ __launch_bounds__(256) void k_mix(const float* __restrict__ dftp,
        const float* __restrict__ specw, unsigned short* __restrict__ mah,
        float* __restrict__ statsr, int l){
    int b = blockIdx.x, t = threadIdx.x;
    __shared__ float xm[4096];               // [32 m][64 ci][2]
    if (t < 128) statsr[b*128 + t] = 0.f;    // zero raw stats for this layer's pass3
    const float* dp = dftp + (size_t)b*8*4096;
    #pragma unroll
    for (int i = 0; i < 16; ++i){
        int e = i*256 + t;                   // e = ci*64 + m2
        float s = 0.f;
        #pragma unroll
        for (int ng = 0; ng < 8; ++ng) s += dp[ng*4096 + e];
        int ci = e >> 6, m2 = e & 63;
        if (m2 < 32) xm[(m2*64 + ci)*2] = s;           // Xr
        else         xm[((m2-32)*64 + ci)*2 + 1] = -s; // Xi = -sum(sin)
    }
    __syncthreads();
    int co = t >> 2, mq = t & 3;
    float yr[8] = {0,0,0,0,0,0,0,0}, yi[8] = {0,0,0,0,0,0,0,0};
    const float* wbase = specw + (size_t)(l*64)*4096 + co*64 + mq*16;
    for (int ci = 0; ci < 64; ++ci){
        const float* wp = wbase + (size_t)ci*4096;
        float4 w0 = *(const float4*)(wp);
        float4 w1v = *(const float4*)(wp + 4);
        float4 w2v = *(const float4*)(wp + 8);
        float4 w3v = *(const float4*)(wp + 12);
        float wr[8] = {w0.x,w0.z,w1v.x,w1v.z,w2v.x,w2v.z,w3v.x,w3v.z};
        float wi[8] = {w0.y,w0.w,w1v.y,w1v.w,w2v.y,w2v.w,w3v.y,w3v.w};
        #pragma unroll
        for (int mm = 0; mm < 8; ++mm){
            int m = mq*8 + mm;
            float2 x = *(const float2*)(xm + (m*64 + ci)*2);
            yr[mm] = fmaf(x.x, wr[mm], fmaf(-x.y, wi[mm], yr[mm]));
            yi[mm] = fmaf(x.x, wi[mm], fmaf( x.y, wr[mm], yi[mm]));
        }
    }
    unsigned short* mb = mah + (size_t)(b*64 + co)*64;
    #pragma unroll
    for (int mm = 0; mm < 8; ++mm){
        int m = mq*8 + mm;
        float sc = (m == 0) ? 0.015625f : 0.03125f;   // (1|2)/4096 * 64
        mb[m]      = f2h(sc * yr[mm]);
        mb[32 + m] = f2h(-0.03125f * yi[mm]);
    }
}

// ---------------- fused pointwise + iDFT (MFMA, swapped operands) ----------------
// Computes H^T tiles: A = [x | tab] (M=n), B = [W ; ma]^T (N=co). Each lane holds
// 4 consecutive n per fragment -> packed uint2 h-stores.
__global__ __launch_bounds__(256, 2) void k_pass3(
        const unsigned short* __restrict__ xT, const unsigned short* __restrict__ tabT,
        const unsigned short* __restrict__ pwwh, const float* __restrict__ pwb,
        const unsigned short* __restrict__ mah, unsigned short* __restrict__ xh,
        float* __restrict__ statsr, int lay)
{
    int b = blockIdx.x, ntg = blockIdx.y;
    int t = threadIdx.x, w = t >> 6, lane = t & 63;
    int lrow = lane & 15, g = lane >> 4;
    int nsl = ntg*256 + w*64;                // this wave's 64-n slab

    half8 A[4][4];                           // [nt][ks]: rows = n
    #pragma unroll
    for (int nt = 0; nt < 4; ++nt){
        int n = nsl + nt*16 + lrow;
        #pragma unroll
        for (int ks = 0; ks < 4; ++ks){
            int k = ks*32 + g*8;
            const unsigned short* src = (k < 64)
                ? (xT   + ((size_t)b*4096 + n)*64 + k)
                : (tabT + (size_t)n*64 + (k - 64));
            A[nt][ks] = *(const half8*)src;
        }
    }
    half8 Bv[4][4];                          // [cot][ks]: cols = co
    #pragma unroll
    for (int cot = 0; cot < 4; ++cot){
        int co = cot*16 + lrow;
        #pragma unroll
        for (int ks = 0; ks < 4; ++ks){
            int k = ks*32 + g*8;
            const unsigned short* src = (k < 64)
                ? (pwwh + ((size_t)lay*64 + co)*64 + k)
                : (mah  + ((size_t)b*64 + co)*64 + (k - 64));
            Bv[cot][ks] = *(const half8*)src;
        }
    }
    fx4 acc[4][4];                           // [nt][cot]
    #pragma unroll
    for (int i = 0; i < 4; ++i)
        #pragma unroll
        for (int j = 0; j < 4; ++j) acc[i][j] = (fx4){0.f,0.f,0.f,0.f};

    #pragma unroll
    for (int ks = 0; ks < 4; ++ks)
        #pragma unroll
        for (int nt = 0; nt < 4; ++nt)
            #pragma unroll
            for (int cot = 0; cot < 4; ++cot)
                acc[nt][cot] = __builtin_amdgcn_mfma_f32_16x16x32_f16(A[nt][ks], Bv[cot][ks], acc[nt][cot], 0, 0, 0);

    // epilogue: +bias, packed uint2 stores, per-cot stats
    float sS[4] = {0,0,0,0}, sQ[4] = {0,0,0,0};
    #pragma unroll
    for (int cot = 0; cot < 4; ++cot){
        int co = cot*16 + lrow;
        float pb = pwb[lay*64 + co];
        unsigned short* hr = xh + ((size_t)(b*64+co))*4096;
        #pragma unroll
        for (int nt = 0; nt < 4; ++nt){
            float h0 = acc[nt][cot][0] + pb;
            float h1 = acc[nt][cot][1] + pb;
            float h2 = acc[nt][cot][2] + pb;
            float h3 = acc[nt][cot][3] + pb;
            uint2 pk;
            pk.x = (unsigned int)f2h(h0) | ((unsigned int)f2h(h1) << 16);
            pk.y = (unsigned int)f2h(h2) | ((unsigned int)f2h(h3) << 16);
            *(uint2*)(hr + nsl + nt*16 + g*4) = pk;
            sS[cot] += (h0 + h1) + (h2 + h3);
            float q = h0*h0;
            q = fmaf(h1, h1, q); q = fmaf(h2, h2, q); q = fmaf(h3, h3, q);
            sQ[cot] += q;
        }
    }
    __shared__ float sred[2][4][64];
    #pragma unroll
    for (int cot = 0; cot < 4; ++cot){
        float s = sS[cot], q = sQ[cot];
        s += __shfl_xor(s, 16); q += __shfl_xor(q, 16);
        s += __shfl_xor(s, 32); q += __shfl_xor(q, 32);
        if (g == 0){
            sred[0][w][cot*16 + lrow] = s;
            sred[1][w][cot*16 + lrow] = q;
        }
    }
    __syncthreads();
    if (t < 64){
        float S = 0.f, Q = 0.f;
        #pragma unroll
        for (int ww = 0; ww < 4; ++ww){ S += sred[0][ww][t]; Q += sred[1][ww][t]; }
        atomicAdd(statsr + (size_t)(b*64+t)*2,     S);
        atomicAdd(statsr + (size_t)(b*64+t)*2 + 1, Q);
    }
}

// ---------------- projection head (8 waves, 8 tiles per wave) ----------------
__global__ __launch_bounds__(512) void k_proj(
        const unsigned short* __restrict__ xT, const unsigned short* __restrict__ w1h,
        const float* __restrict__ b1, const float* __restrict__ w2,
        const float* __restrict__ b2, float* __restrict__ out)
{
    int b = blockIdx.x, ntg = blockIdx.y;
    int t = threadIdx.x, w = t >> 6, lane = t & 63;
    int lrow = lane & 15, g = lane >> 4;
    int o2h = w & 1, nq = w >> 1;
    int nb = ntg*512 + nq*128;

    half8 A[4][2];
    #pragma unroll
    for (int ot = 0; ot < 4; ++ot)
        #pragma unroll
        for (int ks = 0; ks < 2; ++ks)
            A[ot][ks] = *(const half8*)(w1h + (size_t)(o2h*64 + ot*16 + lrow)*64 + ks*32 + g*8);
    float bb[16], wv[16];
    #pragma unroll
    for (int ot = 0; ot < 4; ++ot)
        #pragma unroll
        for (int j = 0; j < 4; ++j){
            int o2 = o2h*64 + ot*16 + g*4 + j;
            bb[ot*4+j] = b1[o2];
            wv[ot*4+j] = w2[o2];
        }
    __shared__ float sred[4][8][2][16];
    for (int tl = 0; tl < 8; ++tl){
        int n = nb + tl*16 + lrow;
        fx4 acc[4];
        #pragma unroll
        for (int i = 0; i < 4; ++i) acc[i] = (fx4){0.f,0.f,0.f,0.f};
        #pragma unroll
        for (int ks = 0; ks < 2; ++ks){
            half8 bf = *(const half8*)(xT + ((size_t)b*4096 + n)*64 + ks*32 + g*8);
            #pragma unroll
            for (int ot = 0; ot < 4; ++ot)
                acc[ot] = __builtin_amdgcn_mfma_f32_16x16x32_f16(A[ot][ks], bf, acc[ot], 0, 0, 0);
        }
        float p = 0.f;
        #pragma unroll
        for (int ot = 0; ot < 4; ++ot)
            #pragma unroll
            for (int j = 0; j < 4; ++j)
                p = fmaf(wv[ot*4+j], gelu_f(acc[ot][j] + bb[ot*4+j]), p);
        p += __shfl_xor(p, 16); p += __shfl_xor(p, 32);
        if (lane < 16) sred[nq][tl][o2h][lane] = p;
    }
    __syncthreads();
    {
        int cl = t & 15, tlf = (t >> 4) & 7, nqf = t >> 7;
        out[(size_t)b*4096 + ntg*512 + t] =
            sred[nqf][tlf][0][cl] + sred[nqf][tlf][1][cl] + b2[0];
    }
}

// ---------------- launch ----------------
extern "C" void kernel_launch(void* const* d_in, const int* in_sizes, int n_in,
                              void* d_out, int out_size, void* d_ws, size_t ws_size,
                              hipStream_t stream) {
    (void)in_sizes; (void)n_in; (void)out_size; (void)ws_size;
    const float* z      = (const float*)d_in[0];
    const float* instp  = (const float*)d_in[1];
    const float* lift_w = (const float*)d_in[2];
    const float* lift_b = (const float*)d_in[3];
    const float* iw1    = (const float*)d_in[4];
    const float* ib1    = (const float*)d_in[5];
    const float* iw2    = (const float*)d_in[6];
    const float* ib2    = (const float*)d_in[7];
    const float* specw  = (const float*)d_in[8];
    const float* pww    = (const float*)d_in[9];
    const float* pwb    = (const float*)d_in[10];
    const float* pj1w   = (const float*)d_in[11];
    const float* pj1b   = (const float*)d_in[12];
    const float* pj2w   = (const float*)d_in[13];
    const float* pj2b   = (const float*)d_in[14];

    float* ws = (float*)d_ws;
    unsigned short* xh    = (unsigned short*)(ws + OFF_XH);
    unsigned short* xT    = (unsigned short*)(ws + OFF_XT);
    unsigned short* tabB  = (unsigned short*)(ws + OFF_TABB);
    unsigned short* tabT  = (unsigned short*)(ws + OFF_TABT);
    unsigned short* mah   = (unsigned short*)(ws + OFF_MAH);
    unsigned short* pwwh  = (unsigned short*)(ws + OFF_PWWH);
    unsigned short* w1h   = (unsigned short*)(ws + OFF_W1H);
    float* cond   = ws + OFF_COND;
    float* statsr = ws + OFF_STATS;
    float* dftp   = ws + OFF_DFTP;
    float* x0     = ws + OFF_X0;
    float* out    = (float*)d_out;

    k_tab  <<<dim3(1024),  dim3(256), 0, stream>>>(tabB, tabT, pww, pwwh, pj1w, w1h);
    k_cond <<<dim3(128),   dim3(64),  0, stream>>>(instp, iw1, ib1, iw2, ib2, cond);
    k_liftc<<<dim3(128,4), dim3(256), 0, stream>>>(z, lift_w, lift_b, cond, x0);

    for (int l = 0; l < 4; ++l){
        if (l == 0)
            k_prep<2,1><<<dim3(128,8), dim3(256), 0, stream>>>(xh, statsr, tabB, x0, xT, dftp);
        else
            k_prep<1,1><<<dim3(128,8), dim3(256), 0, stream>>>(xh, statsr, tabB, x0, xT, dftp);
        k_mix  <<<dim3(128),    dim3(256), 0, stream>>>(dftp, specw, mah, statsr, l);
        k_pass3<<<dim3(128,16), dim3(256), 0, stream>>>(xT, tabT, pwwh, pwb, mah, xh, statsr, l);
    }
    k_prep<1,0><<<dim3(128,8), dim3(256), 0, stream>>>(xh, statsr, tabB, x0, xT, dftp);
    k_proj    <<<dim3(128,8),  dim3(512), 0, stream>>>(xT, w1h, pj1b, pj2w, pj2b, out);
}

// Round 10
// 468.186 us; speedup vs baseline: 3.6126x; 1.1972x over previous
//
#include <hip/hip_runtime.h>
#include <math.h>

// B=128, W=64, L=4096, MODES=32, N_LAYERS=4

typedef _Float16 half8 __attribute__((ext_vector_type(8)));  // 8 fp16 (4 VGPR)
typedef __attribute__((ext_vector_type(4))) float fx4;       // MFMA f32 acc

// fast gelu: tanh/sigmoid form, exp2-folded. Max dev from exact-erf ~5e-4.
__device__ __forceinline__ float gelu_f(float x){
    float u = x*x;
    float a = x * fmaf(-0.1029443f, u, -2.3022083f);   // -2y*log2(e)
    float e = exp2f(a);                                 // e^{-2y}
    float r = __builtin_amdgcn_rcpf(1.0f + e);          // sigmoid(2y)
    return x * r;
}
__device__ __forceinline__ unsigned short f2h(float f){
    union { _Float16 h; unsigned short u; } c;
    c.h = (_Float16)f;
    return c.u;
}
__device__ __forceinline__ float h2f(unsigned short u){
    union { unsigned short u; _Float16 h; } c;
    c.u = u;
    return (float)c.h;
}

// ---------------- workspace layout (float-slot offsets) ----------------
// xh    : fp16 [128][64][4096]  h (channel-major)
// xT    : fp16 [128][4096][64]  normalized x, position-major
// tabB  : fp16 [64][4096]       rows 0-31 cos, 32-63 sin (fwd DFT)
// tabT  : fp16 [4096][64]       transpose, scaled 1/64 (iDFT)
// mah   : fp16 [b][co][64]      iDFT coeffs x64
// pwwh  : fp16 [4][64][64]
// w1h   : fp16 [128][64]
// cond  : f32  [b][64]
// statsr: f32  [b][co][2]       RAW (S, Q) accumulated by pass3 atomics
// dftp  : f32  [b][8][64 ci][64 m2]
// x0    : f32  [b][64 wc][64 pos]  lift output (pre-interp)
static const size_t OFF_XH    = 0;
static const size_t OFF_XT    = 16777216;
static const size_t OFF_TABB  = 33554432;
static const size_t OFF_TABT  = 33685504;
static const size_t OFF_MAH   = 33816576;   // 262,144 slots
static const size_t OFF_PWWH  = 34078720;   // 8,192
static const size_t OFF_W1H   = 34086912;   // 4,096
static const size_t OFF_COND  = 34091008;   // 8,192
static const size_t OFF_STATS = 34099200;   // 16,384
static const size_t OFF_DFTP  = 34115584;   // 4,194,304
static const size_t OFF_X0    = 38309888;   // 524,288
// end = 38,834,176 slots = 155.3 MB (< proven 157.4 MB footprint)

// ---------------- trig tables + weight fp16 conversion ----------------
__global__ void k_tab(unsigned short* __restrict__ tabB, unsigned short* __restrict__ tabT,
                      const float* __restrict__ pww, unsigned short* __restrict__ pwwh,
                      const float* __restrict__ pj1w, unsigned short* __restrict__ w1h){
    int t = blockIdx.x*256 + threadIdx.x;        // 262144
    if (t < 16384) pwwh[t] = f2h(pww[t]);
    if (t < 8192)  w1h[t]  = f2h(pj1w[t]);
    int m2 = t >> 12, n = t & 4095;
    int m = m2 & 31;
    int r = (m*n) & 4095;
    int r2 = (r >= 2048) ? (r - 4096) : r;       // fold to [-pi, pi)
    float a = (float)r2 * 1.5339807878856412e-3f;   // 2*pi/4096
    float v = (m2 >= 32) ? sinf(a) : cosf(a);
    tabB[(size_t)m2*4096 + n] = f2h(v);
    tabT[(size_t)n*64 + m2]   = f2h(v * 0.015625f);
}

// ---------------- conditioning MLP ----------------
__global__ __launch_bounds__(64) void k_cond(const float* __restrict__ instp,
        const float* __restrict__ w1, const float* __restrict__ b1,
        const float* __restrict__ w2, const float* __restrict__ b2,
        float* __restrict__ cond){
    int b = blockIdx.x, tid = threadIdx.x;
    __shared__ float ipl[8];
    __shared__ float tl[64];
    if (tid < 8) ipl[tid] = instp[b*8 + tid];
    __syncthreads();
    float s = b1[tid];
    #pragma unroll
    for (int k = 0; k < 8; ++k) s = fmaf(ipl[k], w1[k*64 + tid], s);
    tl[tid] = gelu_f(s);
    __syncthreads();
    float c = b2[tid];
    #pragma unroll 8
    for (int j = 0; j < 64; ++j) c = fmaf(tl[j], w2[j*64 + tid], c);
    cond[b*64 + tid] = c;
}

// ---------------- lift core: x0 = z @ lift_w + lb + cond (f32, 2 MB) ----------------
// grid (128 b, 4 q), 256 thr.
__global__ __launch_bounds__(256) void k_liftc(const float* __restrict__ z,
        const float* __restrict__ lw, const float* __restrict__ lb,
        const float* __restrict__ cond, float* __restrict__ x0){
    int b = blockIdx.x, q = blockIdx.y;
    int t = threadIdx.x;
    __shared__ float zl[128];
    if (t < 128) zl[t] = z[b*128 + t];
    __syncthreads();
    #pragma unroll
    for (int i = 0; i < 4; ++i){
        int e = q*1024 + i*256 + t;            // e = wc*64 + pos
        float s = lb[e];
        #pragma unroll 8
        for (int d = 0; d < 128; ++d)
            s = fmaf(zl[d], lw[(size_t)d*4096 + e], s);
        x0[(size_t)b*4096 + e] = s + cond[b*64 + (e >> 6)];
    }
}

// ---------------- prep: (interp | norm+gelu) -> x, transpose-store xT, fwd-DFT ----------
// MODE: 1 = norm+gelu from xh; 2 = inline linear-interp from x0 (layer 0).
template<int MODE, int DODFT>
__global__ __launch_bounds__(256) void k_prep(
        const unsigned short* __restrict__ xhp, const float* __restrict__ statsr,
        const unsigned short* __restrict__ tabB, const float* __restrict__ x0,
        unsigned short* __restrict__ xT, float* __restrict__ dftp)
{
    int b = blockIdx.x, ng = blockIdx.y;
    int t = threadIdx.x;
    int w = t >> 6, lane = t & 63;
    int lrow = lane & 15, g = lane >> 4;
    __shared__ __align__(16) unsigned short xl[2][4096];
    __shared__ float xs[(MODE == 2) ? 65*64 : 1];   // [co][64+1 pad]
    int co = t >> 2, nq = t & 3;
    float mu = 0.f, rs = 1.f;
    if (MODE == 1){
        float2 sr = *(const float2*)(statsr + (size_t)(b*64+co)*2);
        mu = sr.x * (1.f/4096.f);
        float var = fmaf(sr.y, 1.f/4096.f, -mu*mu);
        rs = rsqrtf(var + 1e-5f);
    }
    if (MODE == 2){
        const float* xb0 = x0 + (size_t)b*4096;
        #pragma unroll
        for (int i = 0; i < 16; ++i){
            int idx = i*256 + t;
            xs[(idx >> 6)*65 + (idx & 63)] = xb0[idx];
        }
        __syncthreads();
    }
    fx4 acc[4];
    #pragma unroll
    for (int i = 0; i < 4; ++i) acc[i] = (fx4){0.f,0.f,0.f,0.f};

    const unsigned short* hrow = xhp + ((size_t)(b*64+co))*4096 + ng*512 + nq*16;
    unsigned short* xtbase = xT + ((size_t)b*4096 + (size_t)ng*512)*64;

    uint4 cA, cB;
    if (MODE == 1){ cA = *(const uint4*)(hrow); cB = *(const uint4*)(hrow + 8); }
    for (int it = 0; it < 8; ++it){
        int n0 = ng*512 + it*64;
        char* xb = (char*)(&xl[it & 1][0]);
        uint4 nA, nB;
        if (MODE == 1 && it < 7){                 // prefetch next iter's tile
            nA = *(const uint4*)(hrow + (it+1)*64);
            nB = *(const uint4*)(hrow + (it+1)*64 + 8);
        }
        unsigned int pk[8];
        if (MODE == 1){
            unsigned int hu[8] = {cA.x,cA.y,cA.z,cA.w,cB.x,cB.y,cB.z,cB.w};
            #pragma unroll
            for (int i = 0; i < 8; ++i){
                float f0 = h2f((unsigned short)(hu[i] & 0xFFFFu));
                float f1 = h2f((unsigned short)(hu[i] >> 16));
                f0 = gelu_f((f0 - mu)*rs);
                f1 = gelu_f((f1 - mu)*rs);
                pk[i] = (unsigned int)f2h(f0) | ((unsigned int)f2h(f1) << 16);
            }
        } else {                                  // MODE == 2: inline interp from x0
            const float* xr = xs + co*65;
            #pragma unroll
            for (int i = 0; i < 8; ++i){
                float v[2];
                #pragma unroll
                for (int q = 0; q < 2; ++q){
                    int n = n0 + nq*16 + i*2 + q;
                    float src = (n + 0.5f)*0.015625f - 0.5f;
                    src = fminf(fmaxf(src, 0.0f), 63.0f);
                    int i0 = (int)src;
                    int i1 = (i0 + 1 > 63) ? 63 : (i0 + 1);
                    float wt = src - (float)i0;
                    v[q] = xr[i0] + wt*(xr[i1] - xr[i0]);
                }
                pk[i] = (unsigned int)f2h(v[0]) | ((unsigned int)f2h(v[1]) << 16);
            }
        }
        unsigned int base = (unsigned int)co*128 + (unsigned int)nq*32;
        unsigned int sw = (unsigned int)((co & 7) << 4);
        *(uint4*)(xb + ((base +  0) ^ sw)) = make_uint4(pk[0],pk[1],pk[2],pk[3]);
        *(uint4*)(xb + ((base + 16) ^ sw)) = make_uint4(pk[4],pk[5],pk[6],pk[7]);
        __syncthreads();

        if (DODFT){
            int m0 = w*16;
            #pragma unroll
            for (int ks = 0; ks < 2; ++ks){
                int kk = ks*32 + g*8;
                half8 af = *(const half8*)(tabB + (size_t)(m0 + lrow)*4096 + n0 + kk);
                #pragma unroll
                for (int ct = 0; ct < 4; ++ct){
                    int row = ct*16 + lrow;
                    unsigned int ba = ((unsigned int)row*128 + (unsigned int)kk*2)
                                      ^ (unsigned int)((row & 7) << 4);
                    half8 bf = *(const half8*)(xb + ba);
                    acc[ct] = __builtin_amdgcn_mfma_f32_16x16x32_f16(af, bf, acc[ct], 0, 0, 0);
                }
            }
        }
        {   // transpose out: xT[b][n][co]
            int n = t & 63, coq = t >> 6;
            unsigned int opk[8];
            #pragma unroll
            for (int i = 0; i < 8; ++i){
                int r0 = coq*16 + 2*i, r1 = r0 + 1;
                unsigned int a0 = ((unsigned int)r0*128 + (unsigned int)n*2)
                                  ^ (unsigned int)((r0 & 7) << 4);
                unsigned int a1 = ((unsigned int)r1*128 + (unsigned int)n*2)
                                  ^ (unsigned int)((r1 & 7) << 4);
                unsigned short v0 = *(const unsigned short*)(xb + a0);
                unsigned short v1 = *(const unsigned short*)(xb + a1);
                opk[i] = (unsigned int)v0 | ((unsigned int)v1 << 16);
            }
            unsigned short* dst = xtbase + (size_t)(it*64 + n)*64 + coq*16;
            *(uint4*)dst       = make_uint4(opk[0],opk[1],opk[2],opk[3]);
            *(uint4*)(dst + 8) = make_uint4(opk[4],opk[5],opk[6],opk[7]);
        }
        if (MODE == 1 && it < 7){ cA = nA; cB = nB; }
        // no second barrier: next iter writes the other LDS buffer
    }
    if (DODFT){
        // dftp layout [b][ng][ci][m2]: j contiguous -> float4 stores
        int m0 = w*16;
        #pragma unroll
        for (int ct = 0; ct < 4; ++ct){
            float4 v = make_float4(acc[ct][0], acc[ct][1], acc[ct][2], acc[ct][3]);
            *(float4*)(dftp + ((size_t)(b*8+ng)*64 + ct*16 + lrow)*64 + m0 + g*4) = v;
        }
    }
}

// ---------------- spectral mix (fused dftred + stats zero), co-split ----------------
// grid (128 b, 4 coq), 256 thr. Thread = (mq=t&3, ciq=(t>>2)&3, co_l=t>>4).
// xm[ci][slot]: slot 0-31 = Xr, 32-63 = Xi (= -sum sin). ciq-reduce via shfl.
__global__ __launch_bounds__(256) void k_mix(const float* __restrict__ dftp,
        const float* __restrict__ specw, unsigned short* __restrict__ mah,
        float* __restrict__ statsr, int l){
    int b = blockIdx.x, coq = blockIdx.y, t = threadIdx.x;
    __shared__ float xm[64*64];              // [ci][64]: r | i
    if (t < 128) statsr[b*128 + t] = 0.f;    // all coq blocks write 0 (benign)
    const float* dp = dftp + (size_t)b*8*4096;
    #pragma unroll
    for (int i = 0; i < 4; ++i){
        int e = i*1024 + t*4;                // e = ci*64 + m2, float4-aligned
        float4 s = make_float4(0.f,0.f,0.f,0.f);
        #pragma unroll
        for (int ng = 0; ng < 8; ++ng){
            float4 v = *(const float4*)(dp + (size_t)ng*4096 + e);
            s.x += v.x; s.y += v.y; s.z += v.z; s.w += v.w;
        }
        if (e & 32){ s.x = -s.x; s.y = -s.y; s.z = -s.z; s.w = -s.w; }  // sin half -> Xi
        *(float4*)(xm + e) = s;
    }
    __syncthreads();
    int mq = t & 3, ciq = (t >> 2) & 3, co_l = t >> 4;
    int co = coq*16 + co_l;
    float yr[8] = {0,0,0,0,0,0,0,0}, yi[8] = {0,0,0,0,0,0,0,0};
    const float* wbase = specw + (size_t)l*262144 + (size_t)co*64 + mq*16;
    #pragma unroll 4
    for (int cil = 0; cil < 16; ++cil){
        int ci = ciq*16 + cil;
        const float* wp = wbase + (size_t)ci*4096;
        float4 w0 = *(const float4*)(wp);
        float4 w1v = *(const float4*)(wp + 4);
        float4 w2v = *(const float4*)(wp + 8);
        float4 w3v = *(const float4*)(wp + 12);
        const float* xc = xm + ci*64 + mq*8;
        float4 r0 = *(const float4*)(xc);
        float4 r1 = *(const float4*)(xc + 4);
        float4 i0 = *(const float4*)(xc + 32);
        float4 i1 = *(const float4*)(xc + 36);
        float wr[8] = {w0.x,w0.z,w1v.x,w1v.z,w2v.x,w2v.z,w3v.x,w3v.z};
        float wi[8] = {w0.y,w0.w,w1v.y,w1v.w,w2v.y,w2v.w,w3v.y,w3v.w};
        float xr[8] = {r0.x,r0.y,r0.z,r0.w,r1.x,r1.y,r1.z,r1.w};
        float xi[8] = {i0.x,i0.y,i0.z,i0.w,i1.x,i1.y,i1.z,i1.w};
        #pragma unroll
        for (int mm = 0; mm < 8; ++mm){
            yr[mm] = fmaf(xr[mm], wr[mm], fmaf(-xi[mm], wi[mm], yr[mm]));
            yi[mm] = fmaf(xr[mm], wi[mm], fmaf( xi[mm], wr[mm], yi[mm]));
        }
    }
    #pragma unroll
    for (int mm = 0; mm < 8; ++mm){
        yr[mm] += __shfl_xor(yr[mm], 4); yr[mm] += __shfl_xor(yr[mm], 8);
        yi[mm] += __shfl_xor(yi[mm], 4); yi[mm] += __shfl_xor(yi[mm], 8);
    }
    if (ciq == 0){
        unsigned short* mb = mah + (size_t)(b*64 + co)*64;
        unsigned int pr[4], pi[4];
        #pragma unroll
        for (int p = 0; p < 4; ++p){
            int m0 = mq*8 + 2*p;
            float s0 = (m0 == 0) ? 0.015625f : 0.03125f;   // (1|2)/4096 * 64
            pr[p] = (unsigned int)f2h(s0*yr[2*p]) | ((unsigned int)f2h(0.03125f*yr[2*p+1]) << 16);
            pi[p] = (unsigned int)f2h(-0.03125f*yi[2*p]) | ((unsigned int)f2h(-0.03125f*yi[2*p+1]) << 16);
        }
        *(uint4*)(mb + mq*8)      = make_uint4(pr[0],pr[1],pr[2],pr[3]);
        *(uint4*)(mb + 32 + mq*8) = make_uint4(pi[0],pi[1],pi[2],pi[3]);
    }
}

// ---------------- fused pointwise + iDFT (MFMA, swapped operands) ----------------
__global__ __launch_bounds__(256, 2) void k_pass3(
        const unsigned short* __restrict__ xT, const unsigned short* __restrict__ tabT,
        const unsigned short* __restrict__ pwwh, const float* __restrict__ pwb,
        const unsigned short* __restrict__ mah, unsigned short* __restrict__ xh,
        float* __restrict__ statsr, int lay)
{
    int b = blockIdx.x, ntg = blockIdx.y;
    int t = threadIdx.x, w = t >> 6, lane = t & 63;
    int lrow = lane & 15, g = lane >> 4;
    int nsl = ntg*256 + w*64;                // this wave's 64-n slab

    half8 A[4][4];                           // [nt][ks]: rows = n
    #pragma unroll
    for (int nt = 0; nt < 4; ++nt){
        int n = nsl + nt*16 + lrow;
        #pragma unroll
        for (int ks = 0; ks < 4; ++ks){
            int k = ks*32 + g*8;
            const unsigned short* src = (k < 64)
                ? (xT   + ((size_t)b*4096 + n)*64 + k)
                : (tabT + (size_t)n*64 + (k - 64));
            A[nt][ks] = *(const half8*)src;
        }
    }
    half8 Bv[4][4];                          // [cot][ks]: cols = co
    #pragma unroll
    for (int cot = 0; cot < 4; ++cot){
        int co = cot*16 + lrow;
        #pragma unroll
        for (int ks = 0; ks < 4; ++ks){
            int k = ks*32 + g*8;
            const unsigned short* src = (k < 64)
                ? (pwwh + ((size_t)lay*64 + co)*64 + k)
                : (mah  + ((size_t)b*64 + co)*64 + (k - 64));
            Bv[cot][ks] = *(const half8*)src;
        }
    }
    fx4 acc[4][4];                           // [nt][cot]
    #pragma unroll
    for (int i = 0; i < 4; ++i)
        #pragma unroll
        for (int j = 0; j < 4; ++j) acc[i][j] = (fx4){0.f,0.f,0.f,0.f};

    #pragma unroll
    for (int ks = 0; ks < 4; ++ks)
        #pragma unroll
        for (int nt = 0; nt < 4; ++nt)
            #pragma unroll
            for (int cot = 0; cot < 4; ++cot)
                acc[nt][cot] = __builtin_amdgcn_mfma_f32_16x16x32_f16(A[nt][ks], Bv[cot][ks], acc[nt][cot], 0, 0, 0);

    // epilogue: +bias, packed uint2 stores, per-cot stats
    float sS[4] = {0,0,0,0}, sQ[4] = {0,0,0,0};
    #pragma unroll
    for (int cot = 0; cot < 4; ++cot){
        int co = cot*16 + lrow;
        float pb = pwb[lay*64 + co];
        unsigned short* hr = xh + ((size_t)(b*64+co))*4096;
        #pragma unroll
        for (int nt = 0; nt < 4; ++nt){
            float h0 = acc[nt][cot][0] + pb;
            float h1 = acc[nt][cot][1] + pb;
            float h2 = acc[nt][cot][2] + pb;
            float h3 = acc[nt][cot][3] + pb;
            uint2 pk;
            pk.x = (unsigned int)f2h(h0) | ((unsigned int)f2h(h1) << 16);
            pk.y = (unsigned int)f2h(h2) | ((unsigned int)f2h(h3) << 16);
            *(uint2*)(hr + nsl + nt*16 + g*4) = pk;
            sS[cot] += (h0 + h1) + (h2 + h3);
            float q = h0*h0;
            q = fmaf(h1, h1, q); q = fmaf(h2, h2, q); q = fmaf(h3, h3, q);
            sQ[cot] += q;
        }
    }
    __shared__ float sred[2][4][64];
    #pragma unroll
    for (int cot = 0; cot < 4; ++cot){
        float s = sS[cot], q = sQ[cot];
        s += __shfl_xor(s, 16); q += __shfl_xor(q, 16);
        s += __shfl_xor(s, 32); q += __shfl_xor(q, 32);
        if (g == 0){
            sred[0][w][cot*16 + lrow] = s;
            sred[1][w][cot*16 + lrow] = q;
        }
    }
    __syncthreads();
    if (t < 64){
        float S = 0.f, Q = 0.f;
        #pragma unroll
        for (int ww = 0; ww < 4; ++ww){ S += sred[0][ww][t]; Q += sred[1][ww][t]; }
        atomicAdd(statsr + (size_t)(b*64+t)*2,     S);
        atomicAdd(statsr + (size_t)(b*64+t)*2 + 1, Q);
    }
}

// ---------------- projection head (8 waves, 8 tiles per wave) ----------------
__global__ __launch_bounds__(512) void k_proj(
        const unsigned short* __restrict__ xT, const unsigned short* __restrict__ w1h,
        const float* __restrict__ b1, const float* __restrict__ w2,
        const float* __restrict__ b2, float* __restrict__ out)
{
    int b = blockIdx.x, ntg = blockIdx.y;
    int t = threadIdx.x, w = t >> 6, lane = t & 63;
    int lrow = lane & 15, g = lane >> 4;
    int o2h = w & 1, nq = w >> 1;
    int nb = ntg*512 + nq*128;

    half8 A[4][2];
    #pragma unroll
    for (int ot = 0; ot < 4; ++ot)
        #pragma unroll
        for (int ks = 0; ks < 2; ++ks)
            A[ot][ks] = *(const half8*)(w1h + (size_t)(o2h*64 + ot*16 + lrow)*64 + ks*32 + g*8);
    float bb[16], wv[16];
    #pragma unroll
    for (int ot = 0; ot < 4; ++ot)
        #pragma unroll
        for (int j = 0; j < 4; ++j){
            int o2 = o2h*64 + ot*16 + g*4 + j;
            bb[ot*4+j] = b1[o2];
            wv[ot*4+j] = w2[o2];
        }
    __shared__ float sred[4][8][2][16];
    for (int tl = 0; tl < 8; ++tl){
        int n = nb + tl*16 + lrow;
        fx4 acc[4];
        #pragma unroll
        for (int i = 0; i < 4; ++i) acc[i] = (fx4){0.f,0.f,0.f,0.f};
        #pragma unroll
        for (int ks = 0; ks < 2; ++ks){
            half8 bf = *(const half8*)(xT + ((size_t)b*4096 + n)*64 + ks*32 + g*8);
            #pragma unroll
            for (int ot = 0; ot < 4; ++ot)
                acc[ot] = __builtin_amdgcn_mfma_f32_16x16x32_f16(A[ot][ks], bf, acc[ot], 0, 0, 0);
        }
        float p = 0.f;
        #pragma unroll
        for (int ot = 0; ot < 4; ++ot)
            #pragma unroll
            for (int j = 0; j < 4; ++j)
                p = fmaf(wv[ot*4+j], gelu_f(acc[ot][j] + bb[ot*4+j]), p);
        p += __shfl_xor(p, 16); p += __shfl_xor(p, 32);
        if (lane < 16) sred[nq][tl][o2h][lane] = p;
    }
    __syncthreads();
    {
        int cl = t & 15, tlf = (t >> 4) & 7, nqf = t >> 7;
        out[(size_t)b*4096 + ntg*512 + t] =
            sred[nqf][tlf][0][cl] + sred[nqf][tlf][1][cl] + b2[0];
    }
}

// ---------------- launch ----------------
extern "C" void kernel_launch(void* const* d_in, const int* in_sizes, int n_in,
                              void* d_out, int out_size, void* d_ws, size_t ws_size,
                              hipStream_t stream) {
    (void)in_sizes; (void)n_in; (void)out_size; (void)ws_size;
    const float* z      = (const float*)d_in[0];
    const float* instp  = (const float*)d_in[1];
    const float* lift_w = (const float*)d_in[2];
    const float* lift_b = (const float*)d_in[3];
    const float* iw1    = (const float*)d_in[4];
    const float* ib1    = (const float*)d_in[5];
    const float* iw2    = (const float*)d_in[6];
    const float* ib2    = (const float*)d_in[7];
    const float* specw  = (const float*)d_in[8];
    const float* pww    = (const float*)d_in[9];
    const float* pwb    = (const float*)d_in[10];
    const float* pj1w   = (const float*)d_in[11];
    const float* pj1b   = (const float*)d_in[12];
    const float* pj2w   = (const float*)d_in[13];
    const float* pj2b   = (const float*)d_in[14];

    float* ws = (float*)d_ws;
    unsigned short* xh    = (unsigned short*)(ws + OFF_XH);
    unsigned short* xT    = (unsigned short*)(ws + OFF_XT);
    unsigned short* tabB  = (unsigned short*)(ws + OFF_TABB);
    unsigned short* tabT  = (unsigned short*)(ws + OFF_TABT);
    unsigned short* mah   = (unsigned short*)(ws + OFF_MAH);
    unsigned short* pwwh  = (unsigned short*)(ws + OFF_PWWH);
    unsigned short* w1h   = (unsigned short*)(ws + OFF_W1H);
    float* cond   = ws + OFF_COND;
    float* statsr = ws + OFF_STATS;
    float* dftp   = ws + OFF_DFTP;
    float* x0     = ws + OFF_X0;
    float* out    = (float*)d_out;

    k_tab  <<<dim3(1024),  dim3(256), 0, stream>>>(tabB, tabT, pww, pwwh, pj1w, w1h);
    k_cond <<<dim3(128),   dim3(64),  0, stream>>>(instp, iw1, ib1, iw2, ib2, cond);
    k_liftc<<<dim3(128,4), dim3(256), 0, stream>>>(z, lift_w, lift_b, cond, x0);

    for (int l = 0; l < 4; ++l){
        if (l == 0)
            k_prep<2,1><<<dim3(128,8), dim3(256), 0, stream>>>(xh, statsr, tabB, x0, xT, dftp);
        else
            k_prep<1,1><<<dim3(128,8), dim3(256), 0, stream>>>(xh, statsr, tabB, x0, xT, dftp);
        k_mix  <<<dim3(128,4),  dim3(256), 0, stream>>>(dftp, specw, mah, statsr, l);
        k_pass3<<<dim3(128,16), dim3(256), 0, stream>>>(xT, tabT, pwwh, pwb, mah, xh, statsr, l);
    }
    k_prep<1,0><<<dim3(128,8), dim3(256), 0, stream>>>(xh, statsr, tabB, x0, xT, dftp);
    k_proj    <<<dim3(128,8),  dim3(512), 0, stream>>>(xT, w1h, pj1b, pj2w, pj2b, out);
}